// Round 3
// baseline (540.640 us; speedup 1.0000x reference)
//
#include <hip/hip_runtime.h>
#include <hip/hip_bf16.h>
#include <cstdint>
#include <cstddef>

#define B_ 2
#define S_ 2048
#define NH_ 16
#define NKV_ 4
#define HD_ 128
#define QDIM_ 2048
#define KVDIM_ 512
#define QKV_ 3072

typedef __attribute__((ext_vector_type(8))) short short8;
typedef __attribute__((ext_vector_type(4))) float float4v;

__device__ __forceinline__ float bf2f(short u) {
  union { unsigned int i; float f; } v;
  v.i = ((unsigned int)(unsigned short)u) << 16;
  return v.f;
}
__device__ __forceinline__ short f2bf(float f) {
  union { float f; unsigned int i; } v; v.f = f;
  unsigned int x = v.i;
  x += 0x7fffu + ((x >> 16) & 1u);   // RNE
  return (short)(x >> 16);
}

// Load 8 contiguous elements starting at element offset `off`, as bf16x8.
// F32 inputs are converted (RNE) on the fly.
template <bool F32>
__device__ __forceinline__ short8 ld8(const void* p, size_t off) {
  if constexpr (F32) {
    const float* f = (const float*)p + off;
    float4v a = *(const float4v*)(f);
    float4v b = *(const float4v*)(f + 4);
    short8 r;
#pragma unroll
    for (int e = 0; e < 4; ++e) { r[e] = f2bf(a[e]); r[4 + e] = f2bf(b[e]); }
    return r;
  } else {
    return *(const short8*)((const short*)p + off);
  }
}

// ---------------------------------------------------------------------------
// NT GEMM: C[M,N] = A[M,K] * B[N,K]^T. A/B fp32-or-bf16 in (bf16 compute,
// fp32 acc), C fp32-or-bf16 out. 128x128 tile, BK=32, 256 thr (4 waves 2x2).
// Register->LDS staging with dtype conversion in the staging path.
// ---------------------------------------------------------------------------
template <int N, int K, bool AF32, bool BF32, bool CF32>
__global__ __launch_bounds__(256)
void gemm_nt(const void* __restrict__ Ap, const void* __restrict__ Bp,
             void* __restrict__ Cp) {
  __shared__ __align__(16) short sA[128 * 32];
  __shared__ __align__(16) short sB[128 * 32];
  const int tid = threadIdx.x;
  const int m0 = blockIdx.y * 128, n0 = blockIdx.x * 128;
  const int wave = tid >> 6, lane = tid & 63;
  const int wm = (wave & 1) << 6, wn = (wave >> 1) << 6;
  const int lm = lane & 15, kg = lane >> 4;

  float4v acc[4][4];
#pragma unroll
  for (int i = 0; i < 4; ++i)
#pragma unroll
    for (int j = 0; j < 4; ++j)
      acc[i][j] = (float4v){0.f, 0.f, 0.f, 0.f};

  // staging map: thread t owns 8-elem chunk t and t+256 of each 128x32 tile
  const int r0 = tid >> 2, c0 = tid & 3;
  const size_t offA0 = (size_t)(m0 + r0) * K + c0 * 8;
  const size_t offA1 = offA0 + (size_t)64 * K;
  const size_t offB0 = (size_t)(n0 + r0) * K + c0 * 8;
  const size_t offB1 = offB0 + (size_t)64 * K;

  for (int k0 = 0; k0 < K; k0 += 32) {
    short8 va0 = ld8<AF32>(Ap, offA0 + k0);
    short8 va1 = ld8<AF32>(Ap, offA1 + k0);
    short8 vb0 = ld8<BF32>(Bp, offB0 + k0);
    short8 vb1 = ld8<BF32>(Bp, offB1 + k0);
    __syncthreads();   // prior iter's LDS reads complete before overwrite
    *(short8*)(sA + tid * 8)        = va0;
    *(short8*)(sA + 2048 + tid * 8) = va1;
    *(short8*)(sB + tid * 8)        = vb0;
    *(short8*)(sB + 2048 + tid * 8) = vb1;
    __syncthreads();

    short8 a[4], b[4];
#pragma unroll
    for (int i = 0; i < 4; ++i)
      a[i] = *(const short8*)(sA + (wm + i * 16 + lm) * 32 + kg * 8);
#pragma unroll
    for (int j = 0; j < 4; ++j)
      b[j] = *(const short8*)(sB + (wn + j * 16 + lm) * 32 + kg * 8);
#pragma unroll
    for (int i = 0; i < 4; ++i)
#pragma unroll
      for (int j = 0; j < 4; ++j)
        acc[i][j] = __builtin_amdgcn_mfma_f32_16x16x32_bf16(a[i], b[j], acc[i][j], 0, 0, 0);
  }

  // C/D layout: col = lane&15, row = (lane>>4)*4 + reg
#pragma unroll
  for (int i = 0; i < 4; ++i) {
    const int rb = m0 + wm + i * 16 + kg * 4;
#pragma unroll
    for (int j = 0; j < 4; ++j) {
      const int cc = n0 + wn + j * 16 + lm;
#pragma unroll
      for (int r = 0; r < 4; ++r) {
        if constexpr (CF32)
          ((float*)Cp)[(size_t)(rb + r) * N + cc] = acc[i][j][r];
        else
          ((short*)Cp)[(size_t)(rb + r) * N + cc] = f2bf(acc[i][j][r]);
      }
    }
  }
}

// ---------------------------------------------------------------------------
// RoPE + split/layout: xqkv[4096][3072] (bf16) -> Qr[B][NH][S][HD] (rope),
// Kr[B][NKV][S][HD] (rope), Vv[B][NKV][S][HD] (copy). freqs is fp32.
// out[2i] = t0*f[2i+1] - t1*f[2i]; out[2i+1] = t0*f[2i] + t1*f[2i+1]
// ---------------------------------------------------------------------------
__global__ void rope_split(const short* __restrict__ xqkv, const float* __restrict__ freqs,
                           short* __restrict__ Qr, short* __restrict__ Kr,
                           short* __restrict__ Vv) {
  const int id = blockIdx.x * 256 + threadIdx.x;
  const int i = id / (QKV_ / 8);   // token 0..4095
  const int c8 = id % (QKV_ / 8);
  const int col = c8 * 8;
  const int b = i >> 11, s = i & (S_ - 1);
  short8 xv = *(const short8*)(xqkv + (size_t)i * QKV_ + col);
  if (col < QDIM_ + KVDIM_) {
    int d;
    short* dst;
    if (col < QDIM_) {
      int hh = col >> 7; d = col & 127;
      dst = Qr + ((size_t)(b * NH_ + hh) * S_ + s) * HD_ + d;
    } else {
      int cc = col - QDIM_;
      int hh = cc >> 7; d = cc & 127;
      dst = Kr + ((size_t)(b * NKV_ + hh) * S_ + s) * HD_ + d;
    }
    const float* fp = freqs + (size_t)s * HD_ + d;
    float4v fa = *(const float4v*)(fp);
    float4v fb = *(const float4v*)(fp + 4);
    float ff[8] = {fa[0], fa[1], fa[2], fa[3], fb[0], fb[1], fb[2], fb[3]};
    short8 ov;
#pragma unroll
    for (int pp = 0; pp < 4; ++pp) {
      float t0 = bf2f(xv[2 * pp]), t1 = bf2f(xv[2 * pp + 1]);
      float f0 = ff[2 * pp], f1 = ff[2 * pp + 1];
      ov[2 * pp]     = f2bf(t0 * f1 - t1 * f0);
      ov[2 * pp + 1] = f2bf(t0 * f0 + t1 * f1);
    }
    *(short8*)dst = ov;
  } else {
    int cc = col - QDIM_ - KVDIM_;
    int hh = cc >> 7, d = cc & 127;
    *(short8*)(Vv + ((size_t)(b * NKV_ + hh) * S_ + s) * HD_ + d) = xv;
  }
}

// ---------------------------------------------------------------------------
// Flash attention, causal, GQA. TQ=128 (wave owns 32 rows), TK=64.
// Q frags in registers; K in padded LDS [64][136]; V transposed in LDS
// [128][72]; P round-trip through LDS [128][72] (C-layout -> A-layout).
// All bf16 internal. Output: attn[b*S+q][h*HD+d] bf16.
// ---------------------------------------------------------------------------
#define TQ 128
#define TK 64
#define KP 136   // sK row stride (128 + 8 pad; 272B, b128-aligned)
#define VP 72    // sVt/sP row stride (64 + 8 pad; 144B)

__global__ __launch_bounds__(256)
void attn_causal(const short* __restrict__ Q, const short* __restrict__ K,
                 const short* __restrict__ V, short* __restrict__ O) {
  const int qt = blockIdx.x, bh = blockIdx.y;
  const int b = bh >> 4, h = bh & 15;
  const int kvh = h >> 2;
  const int q0 = qt * TQ;
  const int tid = threadIdx.x, wave = tid >> 6, lane = tid & 63;
  const int lm = lane & 15, kg = lane >> 4;

  __shared__ __align__(16) short sK[TK * KP];
  __shared__ __align__(16) short sVt[HD_ * VP];
  __shared__ __align__(16) short sP[TQ * VP];

  const short* Qb = Q + (size_t)(b * NH_ + h) * S_ * HD_;
  const short* Kb = K + (size_t)(b * NKV_ + kvh) * S_ * HD_;
  const short* Vb = V + (size_t)(b * NKV_ + kvh) * S_ * HD_;

  // Q A-frags: A[m=lane&15][k=kg*8+j]; rows wave*32 + i*16 + lm
  short8 qf[2][4];
#pragma unroll
  for (int i = 0; i < 2; ++i)
#pragma unroll
    for (int kk = 0; kk < 4; ++kk)
      qf[i][kk] = *(const short8*)(Qb + (size_t)(q0 + wave * 32 + i * 16 + lm) * HD_ +
                                   kk * 32 + kg * 8);

  float mrow[2][4], lrow[2][4];
  float4v o[2][8];
#pragma unroll
  for (int i = 0; i < 2; ++i) {
#pragma unroll
    for (int r = 0; r < 4; ++r) { mrow[i][r] = -1e9f; lrow[i][r] = 0.f; }
#pragma unroll
    for (int df = 0; df < 8; ++df) o[i][df] = (float4v){0.f, 0.f, 0.f, 0.f};
  }

  const int vdc = tid & 15, vkr = tid >> 4;
  const int ntiles = 2 * qt + 2;   // causal: keys up to q0+127
  for (int j = 0; j < ntiles; ++j) {
    const int k0 = j * TK;
    short8 kv[4];
#pragma unroll
    for (int c = 0; c < 4; ++c) {
      int ch = tid + 256 * c;            // chunk 0..1023
      int row = ch >> 4, kc = ch & 15;
      kv[c] = *(const short8*)(Kb + (size_t)(k0 + row) * HD_ + kc * 8);
    }
    short8 vv[4];
#pragma unroll
    for (int c = 0; c < 4; ++c) {
      int k = c * 16 + vkr;
      vv[c] = *(const short8*)(Vb + (size_t)(k0 + k) * HD_ + vdc * 8);
    }
    __syncthreads();   // prior iter's LDS reads done before restage
#pragma unroll
    for (int c = 0; c < 4; ++c) {
      int ch = tid + 256 * c;
      int row = ch >> 4, kc = ch & 15;
      *(short8*)(sK + row * KP + kc * 8) = kv[c];
    }
#pragma unroll
    for (int c = 0; c < 4; ++c) {
      int k = c * 16 + vkr;
#pragma unroll
      for (int e = 0; e < 8; ++e)
        sVt[(vdc * 8 + e) * VP + k] = vv[c][e];
    }
    __syncthreads();

    // S = Q K^T (contraction over HD=128 in 4 MFMA k-steps)
    float4v sf[2][4];
#pragma unroll
    for (int i = 0; i < 2; ++i)
#pragma unroll
      for (int nj = 0; nj < 4; ++nj) sf[i][nj] = (float4v){0.f, 0.f, 0.f, 0.f};
#pragma unroll
    for (int kk = 0; kk < 4; ++kk) {
      int kd = kk * 4 + kg;
#pragma unroll
      for (int nj = 0; nj < 4; ++nj) {
        int n = nj * 16 + lm;
        short8 bf = *(const short8*)(sK + n * KP + kd * 8);
        sf[0][nj] = __builtin_amdgcn_mfma_f32_16x16x32_bf16(qf[0][kk], bf, sf[0][nj], 0, 0, 0);
        sf[1][nj] = __builtin_amdgcn_mfma_f32_16x16x32_bf16(qf[1][kk], bf, sf[1][nj], 0, 0, 0);
      }
    }

    // online softmax per row (row = kg*4+r within 16-tile; cols at lm lanes)
    const float scale = 0.08838834764831845f;  // 1/sqrt(128)
#pragma unroll
    for (int i = 0; i < 2; ++i) {
#pragma unroll
      for (int r = 0; r < 4; ++r) {
        const int qrow = q0 + wave * 32 + i * 16 + kg * 4 + r;
        float pv[4];
        float mx = -3e38f;
#pragma unroll
        for (int nj = 0; nj < 4; ++nj) {
          int kcol = k0 + nj * 16 + lm;
          float v = (kcol <= qrow) ? sf[i][nj][r] * scale : -3e38f;
          pv[nj] = v;
          mx = fmaxf(mx, v);
        }
        mx = fmaxf(mx, __shfl_xor(mx, 1, 64));
        mx = fmaxf(mx, __shfl_xor(mx, 2, 64));
        mx = fmaxf(mx, __shfl_xor(mx, 4, 64));
        mx = fmaxf(mx, __shfl_xor(mx, 8, 64));
        float mold = mrow[i][r];
        float mnew = fmaxf(mold, mx);
        float alpha = __expf(fminf(mold - mnew, 0.f));
        float rs = 0.f;
#pragma unroll
        for (int nj = 0; nj < 4; ++nj) {
          float e = __expf(fminf(pv[nj] - mnew, 0.f));
          rs += e;
          sP[(wave * 32 + i * 16 + kg * 4 + r) * VP + nj * 16 + lm] = f2bf(e);
        }
        rs += __shfl_xor(rs, 1, 64);
        rs += __shfl_xor(rs, 2, 64);
        rs += __shfl_xor(rs, 4, 64);
        rs += __shfl_xor(rs, 8, 64);
        mrow[i][r] = mnew;
        lrow[i][r] = lrow[i][r] * alpha + rs;
#pragma unroll
        for (int df = 0; df < 8; ++df) o[i][df][r] *= alpha;
      }
    }
    __syncthreads();

    // O += P V  (contraction over TK=64 in 2 MFMA k-steps)
#pragma unroll
    for (int kst = 0; kst < 2; ++kst) {
      short8 pa0 = *(const short8*)(sP + (wave * 32 + lm) * VP + kst * 32 + kg * 8);
      short8 pa1 = *(const short8*)(sP + (wave * 32 + 16 + lm) * VP + kst * 32 + kg * 8);
#pragma unroll
      for (int df = 0; df < 8; ++df) {
        short8 vf = *(const short8*)(sVt + (df * 16 + lm) * VP + kst * 32 + kg * 8);
        o[0][df] = __builtin_amdgcn_mfma_f32_16x16x32_bf16(pa0, vf, o[0][df], 0, 0, 0);
        o[1][df] = __builtin_amdgcn_mfma_f32_16x16x32_bf16(pa1, vf, o[1][df], 0, 0, 0);
      }
    }
  }

  // epilogue: O /= l, write attn[b*S+q][h*HD+d]
#pragma unroll
  for (int i = 0; i < 2; ++i) {
#pragma unroll
    for (int r = 0; r < 4; ++r) {
      float inv = 1.f / lrow[i][r];
      const size_t rowoff =
          (size_t)(b * S_ + q0 + wave * 32 + i * 16 + kg * 4 + r) * QDIM_ + h * HD_;
#pragma unroll
      for (int df = 0; df < 8; ++df)
        O[rowoff + df * 16 + lm] = f2bf(o[i][df][r] * inv);
    }
  }
}

// ---------------------------------------------------------------------------
extern "C" void kernel_launch(void* const* d_in, const int* in_sizes, int n_in,
                              void* d_out, int out_size, void* d_ws, size_t ws_size,
                              hipStream_t stream) {
  const float* x     = (const float*)d_in[0];  // [B,S,D] fp32
  const float* freqs = (const float*)d_in[1];  // [S,HD] fp32
  const float* Wqkv  = (const float*)d_in[2];  // [3072,2048] fp32
  const float* Wo    = (const float*)d_in[3];  // [2048,2048] fp32
  float* out = (float*)d_out;                  // [B,S,D] fp32

  // ws layout (bf16 shorts). attn aliases xqkv (xqkv dead after rope_split).
  short* ws   = (short*)d_ws;
  short* xqkv = ws;                                      // 4096*3072
  short* attn = ws;                                      // 4096*2048 (alias, safe)
  short* Qr   = xqkv + (size_t)4096 * QKV_;              // B*NH*S*HD
  short* Kr   = Qr + (size_t)B_ * NH_ * S_ * HD_;        // B*NKV*S*HD
  short* Vv   = Kr + (size_t)B_ * NKV_ * S_ * HD_;       // B*NKV*S*HD
  // total ~25.2M shorts = 50.3 MB

  gemm_nt<QKV_, 2048, true, true, false>
      <<<dim3(QKV_ / 128, 4096 / 128), 256, 0, stream>>>(x, Wqkv, xqkv);
  rope_split<<<(B_ * S_ * QKV_ / 8) / 256, 256, 0, stream>>>(xqkv, freqs, Qr, Kr, Vv);
  attn_causal<<<dim3(S_ / TQ, B_ * NH_), 256, 0, stream>>>(Qr, Kr, Vv, attn);
  gemm_nt<2048, 2048, false, true, true>
      <<<dim3(2048 / 128, 4096 / 128), 256, 0, stream>>>(attn, Wo, out);
}

// Round 4
// 398.739 us; speedup vs baseline: 1.3559x; 1.3559x over previous
//
#include <hip/hip_runtime.h>
#include <hip/hip_bf16.h>
#include <cstdint>
#include <cstddef>

#define B_ 2
#define S_ 2048
#define NH_ 16
#define NKV_ 4
#define HD_ 128
#define QDIM_ 2048
#define KVDIM_ 512
#define QKV_ 3072

typedef __attribute__((ext_vector_type(8))) short short8;
typedef __attribute__((ext_vector_type(4))) float float4v;

__device__ __forceinline__ float bf2f(short u) {
  union { unsigned int i; float f; } v;
  v.i = ((unsigned int)(unsigned short)u) << 16;
  return v.f;
}
__device__ __forceinline__ short f2bf(float f) {
  union { float f; unsigned int i; } v; v.f = f;
  unsigned int x = v.i;
  x += 0x7fffu + ((x >> 16) & 1u);   // RNE
  return (short)(x >> 16);
}

// Load 8 contiguous elements starting at element offset `off`, as bf16x8.
// F32 inputs are converted (RNE) on the fly.
template <bool F32>
__device__ __forceinline__ short8 ld8(const void* p, size_t off) {
  if constexpr (F32) {
    const float* f = (const float*)p + off;
    float4v a = *(const float4v*)(f);
    float4v b = *(const float4v*)(f + 4);
    short8 r;
#pragma unroll
    for (int e = 0; e < 4; ++e) { r[e] = f2bf(a[e]); r[4 + e] = f2bf(b[e]); }
    return r;
  } else {
    return *(const short8*)((const short*)p + off);
  }
}

// ---------------------------------------------------------------------------
// NT GEMM: C[M,N] = A[M,K] * B[N,K]^T. A/B fp32-or-bf16 in (bf16 compute,
// fp32 acc), C fp32-or-bf16 out. 128x128 tile, BK=32, 256 thr (4 waves 2x2).
// (unchanged from round 3 — passing; GEMM optimization is next round)
// ---------------------------------------------------------------------------
template <int N, int K, bool AF32, bool BF32, bool CF32>
__global__ __launch_bounds__(256)
void gemm_nt(const void* __restrict__ Ap, const void* __restrict__ Bp,
             void* __restrict__ Cp) {
  __shared__ __align__(16) short sA[128 * 32];
  __shared__ __align__(16) short sB[128 * 32];
  const int tid = threadIdx.x;
  const int m0 = blockIdx.y * 128, n0 = blockIdx.x * 128;
  const int wave = tid >> 6, lane = tid & 63;
  const int wm = (wave & 1) << 6, wn = (wave >> 1) << 6;
  const int lm = lane & 15, kg = lane >> 4;

  float4v acc[4][4];
#pragma unroll
  for (int i = 0; i < 4; ++i)
#pragma unroll
    for (int j = 0; j < 4; ++j)
      acc[i][j] = (float4v){0.f, 0.f, 0.f, 0.f};

  const int r0 = tid >> 2, c0 = tid & 3;
  const size_t offA0 = (size_t)(m0 + r0) * K + c0 * 8;
  const size_t offA1 = offA0 + (size_t)64 * K;
  const size_t offB0 = (size_t)(n0 + r0) * K + c0 * 8;
  const size_t offB1 = offB0 + (size_t)64 * K;

  for (int k0 = 0; k0 < K; k0 += 32) {
    short8 va0 = ld8<AF32>(Ap, offA0 + k0);
    short8 va1 = ld8<AF32>(Ap, offA1 + k0);
    short8 vb0 = ld8<BF32>(Bp, offB0 + k0);
    short8 vb1 = ld8<BF32>(Bp, offB1 + k0);
    __syncthreads();
    *(short8*)(sA + tid * 8)        = va0;
    *(short8*)(sA + 2048 + tid * 8) = va1;
    *(short8*)(sB + tid * 8)        = vb0;
    *(short8*)(sB + 2048 + tid * 8) = vb1;
    __syncthreads();

    short8 a[4], b[4];
#pragma unroll
    for (int i = 0; i < 4; ++i)
      a[i] = *(const short8*)(sA + (wm + i * 16 + lm) * 32 + kg * 8);
#pragma unroll
    for (int j = 0; j < 4; ++j)
      b[j] = *(const short8*)(sB + (wn + j * 16 + lm) * 32 + kg * 8);
#pragma unroll
    for (int i = 0; i < 4; ++i)
#pragma unroll
      for (int j = 0; j < 4; ++j)
        acc[i][j] = __builtin_amdgcn_mfma_f32_16x16x32_bf16(a[i], b[j], acc[i][j], 0, 0, 0);
  }

#pragma unroll
  for (int i = 0; i < 4; ++i) {
    const int rb = m0 + wm + i * 16 + kg * 4;
#pragma unroll
    for (int j = 0; j < 4; ++j) {
      const int cc = n0 + wn + j * 16 + lm;
#pragma unroll
      for (int r = 0; r < 4; ++r) {
        if constexpr (CF32)
          ((float*)Cp)[(size_t)(rb + r) * N + cc] = acc[i][j][r];
        else
          ((short*)Cp)[(size_t)(rb + r) * N + cc] = f2bf(acc[i][j][r]);
      }
    }
  }
}

// ---------------------------------------------------------------------------
// RoPE + split/layout (unchanged from round 3).
// ---------------------------------------------------------------------------
__global__ void rope_split(const short* __restrict__ xqkv, const float* __restrict__ freqs,
                           short* __restrict__ Qr, short* __restrict__ Kr,
                           short* __restrict__ Vv) {
  const int id = blockIdx.x * 256 + threadIdx.x;
  const int i = id / (QKV_ / 8);   // token 0..4095
  const int c8 = id % (QKV_ / 8);
  const int col = c8 * 8;
  const int b = i >> 11, s = i & (S_ - 1);
  short8 xv = *(const short8*)(xqkv + (size_t)i * QKV_ + col);
  if (col < QDIM_ + KVDIM_) {
    int d;
    short* dst;
    if (col < QDIM_) {
      int hh = col >> 7; d = col & 127;
      dst = Qr + ((size_t)(b * NH_ + hh) * S_ + s) * HD_ + d;
    } else {
      int cc = col - QDIM_;
      int hh = cc >> 7; d = cc & 127;
      dst = Kr + ((size_t)(b * NKV_ + hh) * S_ + s) * HD_ + d;
    }
    const float* fp = freqs + (size_t)s * HD_ + d;
    float4v fa = *(const float4v*)(fp);
    float4v fb = *(const float4v*)(fp + 4);
    float ff[8] = {fa[0], fa[1], fa[2], fa[3], fb[0], fb[1], fb[2], fb[3]};
    short8 ov;
#pragma unroll
    for (int pp = 0; pp < 4; ++pp) {
      float t0 = bf2f(xv[2 * pp]), t1 = bf2f(xv[2 * pp + 1]);
      float f0 = ff[2 * pp], f1 = ff[2 * pp + 1];
      ov[2 * pp]     = f2bf(t0 * f1 - t1 * f0);
      ov[2 * pp + 1] = f2bf(t0 * f0 + t1 * f1);
    }
    *(short8*)dst = ov;
  } else {
    int cc = col - QDIM_ - KVDIM_;
    int hh = cc >> 7, d = cc & 127;
    *(short8*)(Vv + ((size_t)(b * NKV_ + hh) * S_ + s) * HD_ + d) = xv;
  }
}

// ---------------------------------------------------------------------------
// Flash attention v2. TQ=64 (wave owns 16 q rows), TK=64, paired q-tiles
// (i, 31-i) per block -> every block does exactly 33 k-tile steps (balanced;
// grid 512 = 2 blocks/CU, all co-resident).
// V transpose: d-major ushort global loads (coalesced 128B/wave) + b128 row
// writes into sVt (2-way, free) — replaces the 32-way-conflicted scatter.
// Mask applied only on the diagonal k-tile (wave-uniform branch).
// ---------------------------------------------------------------------------
#define TK 64
#define KP 136   // sK row stride (128 + 8 pad; 272B, b128-aligned)
#define VP 72    // sVt/sP row stride (64 + 8 pad; 144B)

__global__ __launch_bounds__(256)
void attn_causal(const short* __restrict__ Q, const short* __restrict__ K,
                 const short* __restrict__ V, short* __restrict__ O) {
  const int pair = blockIdx.x;   // 0..15
  const int bh = blockIdx.y;     // 0..31
  const int b = bh >> 4, h = bh & 15;
  const int kvh = h >> 2;
  const int tid = threadIdx.x, wave = tid >> 6, lane = tid & 63;
  const int lm = lane & 15, kg = lane >> 4;

  __shared__ __align__(16) short sK[TK * KP];     // K tile [64][128+pad]
  __shared__ __align__(16) short sVt[HD_ * VP];   // V^T tile [128][64+pad]
  __shared__ __align__(16) short sP[64 * VP];     // P tile [64][64+pad]

  const short* Qb = Q + (size_t)(b * NH_ + h) * S_ * HD_;
  const short* Kb = K + (size_t)(b * NKV_ + kvh) * S_ * HD_;
  const short* Vb = V + (size_t)(b * NKV_ + kvh) * S_ * HD_;

  const int vd = tid & 127, vg = tid >> 7;   // V-transpose assignment

  for (int half = 0; half < 2; ++half) {
    const int qt = (half == 0) ? pair : 31 - pair;
    const int q0w = qt * 64 + wave * 16;

    // Q A-frags: A[m=lane&15][k=kg*8+j]
    short8 qf[4];
#pragma unroll
    for (int kk = 0; kk < 4; ++kk)
      qf[kk] = *(const short8*)(Qb + (size_t)(q0w + lm) * HD_ + kk * 32 + kg * 8);

    float mrow[4], lrow[4];
    float4v o[8];
#pragma unroll
    for (int r = 0; r < 4; ++r) { mrow[r] = -1e9f; lrow[r] = 0.f; }
#pragma unroll
    for (int df = 0; df < 8; ++df) o[df] = (float4v){0.f, 0.f, 0.f, 0.f};

    const int ntiles = qt + 1;
    for (int j = 0; j < ntiles; ++j) {
      const int k0 = j * TK;
      // K tile -> regs (coalesced b128)
      short8 kv[4];
#pragma unroll
      for (int c = 0; c < 4; ++c) {
        int ch = tid + 256 * c;        // chunk 0..1023
        int row = ch >> 4, kc = ch & 15;
        kv[c] = *(const short8*)(Kb + (size_t)(k0 + row) * HD_ + kc * 8);
      }
      // V tile d-major -> regs (64 consecutive d per wave-instr = 128B coalesced)
      unsigned short vvv[4][8];
#pragma unroll
      for (int c = 0; c < 4; ++c) {
        int kc = vg * 4 + c;
#pragma unroll
        for (int jj = 0; jj < 8; ++jj)
          vvv[c][jj] = (unsigned short)Vb[(size_t)(k0 + kc * 8 + jj) * HD_ + vd];
      }
      __syncthreads();   // prior iter's LDS reads done before restage
#pragma unroll
      for (int c = 0; c < 4; ++c) {
        int ch = tid + 256 * c;
        int row = ch >> 4, kc = ch & 15;
        *(short8*)(sK + row * KP + kc * 8) = kv[c];
      }
#pragma unroll
      for (int c = 0; c < 4; ++c) {
        int kc = vg * 4 + c;
        short8 w;
#pragma unroll
        for (int jj = 0; jj < 8; ++jj) w[jj] = (short)vvv[c][jj];
        *(short8*)(sVt + vd * VP + kc * 8) = w;   // sVt[d][k] = V[k][d]
      }
      __syncthreads();

      // S = Q K^T (4 k-steps over HD=128)
      float4v sf[4];
#pragma unroll
      for (int nj = 0; nj < 4; ++nj) sf[nj] = (float4v){0.f, 0.f, 0.f, 0.f};
#pragma unroll
      for (int kk = 0; kk < 4; ++kk) {
        int kd = kk * 4 + kg;
#pragma unroll
        for (int nj = 0; nj < 4; ++nj) {
          short8 bf = *(const short8*)(sK + (nj * 16 + lm) * KP + kd * 8);
          sf[nj] = __builtin_amdgcn_mfma_f32_16x16x32_bf16(qf[kk], bf, sf[nj], 0, 0, 0);
        }
      }

      // online softmax; rows kg*4+r, cols nj*16+lm
      const float scale = 0.08838834764831845f;  // 1/sqrt(128)
      const bool diag = (j == qt);
#pragma unroll
      for (int r = 0; r < 4; ++r) {
        float pv[4];
        float mx = -3e38f;
        if (diag) {
          const int qloc = wave * 16 + kg * 4 + r;   // q offset within the 64-block... keys local
#pragma unroll
          for (int nj = 0; nj < 4; ++nj) {
            float v = ((nj * 16 + lm) <= qloc) ? sf[nj][r] * scale : -3e38f;
            pv[nj] = v; mx = fmaxf(mx, v);
          }
        } else {
#pragma unroll
          for (int nj = 0; nj < 4; ++nj) {
            float v = sf[nj][r] * scale;
            pv[nj] = v; mx = fmaxf(mx, v);
          }
        }
        mx = fmaxf(mx, __shfl_xor(mx, 1, 64));
        mx = fmaxf(mx, __shfl_xor(mx, 2, 64));
        mx = fmaxf(mx, __shfl_xor(mx, 4, 64));
        mx = fmaxf(mx, __shfl_xor(mx, 8, 64));
        float mold = mrow[r];
        float mnew = fmaxf(mold, mx);
        float alpha = __expf(fminf(mold - mnew, 0.f));
        float rs = 0.f;
#pragma unroll
        for (int nj = 0; nj < 4; ++nj) {
          float e = __expf(fminf(pv[nj] - mnew, 0.f));
          rs += e;
          sP[(wave * 16 + kg * 4 + r) * VP + nj * 16 + lm] = f2bf(e);
        }
        rs += __shfl_xor(rs, 1, 64);
        rs += __shfl_xor(rs, 2, 64);
        rs += __shfl_xor(rs, 4, 64);
        rs += __shfl_xor(rs, 8, 64);
        mrow[r] = mnew;
        lrow[r] = lrow[r] * alpha + rs;
#pragma unroll
        for (int df = 0; df < 8; ++df) o[df][r] *= alpha;
      }
      // sP is wave-private (rows wave*16..+15): no barrier needed before PV.

      // O += P V (2 k-steps over TK=64)
#pragma unroll
      for (int kst = 0; kst < 2; ++kst) {
        short8 pa = *(const short8*)(sP + (wave * 16 + lm) * VP + kst * 32 + kg * 8);
#pragma unroll
        for (int df = 0; df < 8; ++df) {
          short8 vf = *(const short8*)(sVt + (df * 16 + lm) * VP + kst * 32 + kg * 8);
          o[df] = __builtin_amdgcn_mfma_f32_16x16x32_bf16(pa, vf, o[df], 0, 0, 0);
        }
      }
    }

    // epilogue: O /= l, write attn[b*S+q][h*HD+d]
#pragma unroll
    for (int r = 0; r < 4; ++r) {
      float inv = 1.f / lrow[r];
      const size_t rowoff =
          (size_t)(b * S_ + q0w + kg * 4 + r) * QDIM_ + h * HD_;
#pragma unroll
      for (int df = 0; df < 8; ++df)
        O[rowoff + df * 16 + lm] = f2bf(o[df][r] * inv);
    }
  }
}

// ---------------------------------------------------------------------------
extern "C" void kernel_launch(void* const* d_in, const int* in_sizes, int n_in,
                              void* d_out, int out_size, void* d_ws, size_t ws_size,
                              hipStream_t stream) {
  const float* x     = (const float*)d_in[0];  // [B,S,D] fp32
  const float* freqs = (const float*)d_in[1];  // [S,HD] fp32
  const float* Wqkv  = (const float*)d_in[2];  // [3072,2048] fp32
  const float* Wo    = (const float*)d_in[3];  // [2048,2048] fp32
  float* out = (float*)d_out;                  // [B,S,D] fp32

  // ws layout (bf16 shorts). attn aliases xqkv (xqkv dead after rope_split).
  short* ws   = (short*)d_ws;
  short* xqkv = ws;                                      // 4096*3072
  short* attn = ws;                                      // 4096*2048 (alias, safe)
  short* Qr   = xqkv + (size_t)4096 * QKV_;              // B*NH*S*HD
  short* Kr   = Qr + (size_t)B_ * NH_ * S_ * HD_;        // B*NKV*S*HD
  short* Vv   = Kr + (size_t)B_ * NKV_ * S_ * HD_;       // B*NKV*S*HD
  // total ~25.2M shorts = 50.3 MB

  gemm_nt<QKV_, 2048, true, true, false>
      <<<dim3(QKV_ / 128, 4096 / 128), 256, 0, stream>>>(x, Wqkv, xqkv);
  rope_split<<<(B_ * S_ * QKV_ / 8) / 256, 256, 0, stream>>>(xqkv, freqs, Qr, Kr, Vv);
  attn_causal<<<dim3(16, B_ * NH_), 256, 0, stream>>>(Qr, Kr, Vv, attn);
  gemm_nt<2048, 2048, false, true, true>
      <<<dim3(2048 / 128, 4096 / 128), 256, 0, stream>>>(attn, Wo, out);
}

// Round 5
// 350.334 us; speedup vs baseline: 1.5432x; 1.1382x over previous
//
#include <hip/hip_runtime.h>
#include <hip/hip_bf16.h>
#include <cstdint>
#include <cstddef>

#define B_ 2
#define S_ 2048
#define NH_ 16
#define NKV_ 4
#define HD_ 128
#define QDIM_ 2048
#define KVDIM_ 512
#define QKV_ 3072

typedef __attribute__((ext_vector_type(8))) short short8;
typedef __attribute__((ext_vector_type(4))) float float4v;

__device__ __forceinline__ float bf2f(short u) {
  union { unsigned int i; float f; } v;
  v.i = ((unsigned int)(unsigned short)u) << 16;
  return v.f;
}
__device__ __forceinline__ short f2bf(float f) {
  union { float f; unsigned int i; } v; v.f = f;
  unsigned int x = v.i;
  x += 0x7fffu + ((x >> 16) & 1u);   // RNE
  return (short)(x >> 16);
}

__device__ __forceinline__ void async_copy16(void* lds, const void* g) {
  __builtin_amdgcn_global_load_lds(
      (const __attribute__((address_space(1))) void*)g,
      (__attribute__((address_space(3))) void*)lds, 16, 0, 0);
}

// ---------------------------------------------------------------------------
// fp32 -> bf16 convert (HBM-bound). n8 = element count / 8.
// ---------------------------------------------------------------------------
__global__ void f32_to_bf16(const float* __restrict__ src, short* __restrict__ dst,
                            int n8) {
  int id = blockIdx.x * 256 + threadIdx.x;
  if (id >= n8) return;
  const float* f = src + (size_t)id * 8;
  float4v a = *(const float4v*)(f);
  float4v b = *(const float4v*)(f + 4);
  short8 r;
#pragma unroll
  for (int e = 0; e < 4; ++e) { r[e] = f2bf(a[e]); r[4 + e] = f2bf(b[e]); }
  *(short8*)(dst + (size_t)id * 8) = r;
}

// ---------------------------------------------------------------------------
// NT GEMM, pure bf16 operands: C[M,N] = A[M,K] * B[N,K]^T, fp32 acc.
// m97 structure: 128x128 tile, BK=32, 256 thr (4 waves 2x2),
// global_load_lds width=16 staging, 2-barrier K-loop.
// ---------------------------------------------------------------------------
template <int N, int K, bool CF32>
__global__ __launch_bounds__(256)
void gemm_nt_bf16(const short* __restrict__ A, const short* __restrict__ Bm,
                  void* __restrict__ Cp) {
  __shared__ __align__(16) short sA[128 * 32];
  __shared__ __align__(16) short sB[128 * 32];
  const int tid = threadIdx.x;
  const int m0 = blockIdx.y * 128, n0 = blockIdx.x * 128;
  const int wave = tid >> 6, lane = tid & 63;
  const int wm = (wave & 1) << 6, wn = (wave >> 1) << 6;
  const int lm = lane & 15, kg = lane >> 4;

  float4v acc[4][4];
#pragma unroll
  for (int i = 0; i < 4; ++i)
#pragma unroll
    for (int j = 0; j < 4; ++j)
      acc[i][j] = (float4v){0.f, 0.f, 0.f, 0.f};

  // staging map: thread t owns 16B chunk t and t+256 of each 128x32 tile
  const int r0 = tid >> 2, c0 = tid & 3;
  const short* gA0 = A + (size_t)(m0 + r0) * K + c0 * 8;
  const short* gA1 = gA0 + (size_t)64 * K;
  const short* gB0 = Bm + (size_t)(n0 + r0) * K + c0 * 8;
  const short* gB1 = gB0 + (size_t)64 * K;
  short* lA0 = sA + tid * 8;
  short* lA1 = sA + 2048 + tid * 8;
  short* lB0 = sB + tid * 8;
  short* lB1 = sB + 2048 + tid * 8;

  for (int k0 = 0; k0 < K; k0 += 32) {
    async_copy16(lA0, gA0 + k0);
    async_copy16(lA1, gA1 + k0);
    async_copy16(lB0, gB0 + k0);
    async_copy16(lB1, gB1 + k0);
    __syncthreads();   // drains vmcnt (global_load_lds) before LDS reads

    short8 a[4], b[4];
#pragma unroll
    for (int i = 0; i < 4; ++i)
      a[i] = *(const short8*)(sA + (wm + i * 16 + lm) * 32 + kg * 8);
#pragma unroll
    for (int j = 0; j < 4; ++j)
      b[j] = *(const short8*)(sB + (wn + j * 16 + lm) * 32 + kg * 8);
#pragma unroll
    for (int i = 0; i < 4; ++i)
#pragma unroll
      for (int j = 0; j < 4; ++j)
        acc[i][j] = __builtin_amdgcn_mfma_f32_16x16x32_bf16(a[i], b[j], acc[i][j], 0, 0, 0);
    __syncthreads();   // LDS reads complete before next stage overwrites
  }

  // C/D layout: col = lane&15, row = (lane>>4)*4 + reg
#pragma unroll
  for (int i = 0; i < 4; ++i) {
    const int rb = m0 + wm + i * 16 + kg * 4;
#pragma unroll
    for (int j = 0; j < 4; ++j) {
      const int cc = n0 + wn + j * 16 + lm;
#pragma unroll
      for (int r = 0; r < 4; ++r) {
        if constexpr (CF32)
          ((float*)Cp)[(size_t)(rb + r) * N + cc] = acc[i][j][r];
        else
          ((short*)Cp)[(size_t)(rb + r) * N + cc] = f2bf(acc[i][j][r]);
      }
    }
  }
}

// ---------------------------------------------------------------------------
// RoPE + split/layout (unchanged).
// ---------------------------------------------------------------------------
__global__ void rope_split(const short* __restrict__ xqkv, const float* __restrict__ freqs,
                           short* __restrict__ Qr, short* __restrict__ Kr,
                           short* __restrict__ Vv) {
  const int id = blockIdx.x * 256 + threadIdx.x;
  const int i = id / (QKV_ / 8);   // token 0..4095
  const int c8 = id % (QKV_ / 8);
  const int col = c8 * 8;
  const int b = i >> 11, s = i & (S_ - 1);
  short8 xv = *(const short8*)(xqkv + (size_t)i * QKV_ + col);
  if (col < QDIM_ + KVDIM_) {
    int d;
    short* dst;
    if (col < QDIM_) {
      int hh = col >> 7; d = col & 127;
      dst = Qr + ((size_t)(b * NH_ + hh) * S_ + s) * HD_ + d;
    } else {
      int cc = col - QDIM_;
      int hh = cc >> 7; d = cc & 127;
      dst = Kr + ((size_t)(b * NKV_ + hh) * S_ + s) * HD_ + d;
    }
    const float* fp = freqs + (size_t)s * HD_ + d;
    float4v fa = *(const float4v*)(fp);
    float4v fb = *(const float4v*)(fp + 4);
    float ff[8] = {fa[0], fa[1], fa[2], fa[3], fb[0], fb[1], fb[2], fb[3]};
    short8 ov;
#pragma unroll
    for (int pp = 0; pp < 4; ++pp) {
      float t0 = bf2f(xv[2 * pp]), t1 = bf2f(xv[2 * pp + 1]);
      float f0 = ff[2 * pp], f1 = ff[2 * pp + 1];
      ov[2 * pp]     = f2bf(t0 * f1 - t1 * f0);
      ov[2 * pp + 1] = f2bf(t0 * f0 + t1 * f1);
    }
    *(short8*)dst = ov;
  } else {
    int cc = col - QDIM_ - KVDIM_;
    int hh = cc >> 7, d = cc & 127;
    *(short8*)(Vv + ((size_t)(b * NKV_ + hh) * S_ + s) * HD_ + d) = xv;
  }
}

// ---------------------------------------------------------------------------
// Flash attention v2 (unchanged from round 4 — 126 us, next round's target).
// ---------------------------------------------------------------------------
#define TK 64
#define KP 136
#define VP 72

__global__ __launch_bounds__(256)
void attn_causal(const short* __restrict__ Q, const short* __restrict__ K,
                 const short* __restrict__ V, short* __restrict__ O) {
  const int pair = blockIdx.x;   // 0..15
  const int bh = blockIdx.y;     // 0..31
  const int b = bh >> 4, h = bh & 15;
  const int kvh = h >> 2;
  const int tid = threadIdx.x, wave = tid >> 6, lane = tid & 63;
  const int lm = lane & 15, kg = lane >> 4;

  __shared__ __align__(16) short sK[TK * KP];
  __shared__ __align__(16) short sVt[HD_ * VP];
  __shared__ __align__(16) short sP[64 * VP];

  const short* Qb = Q + (size_t)(b * NH_ + h) * S_ * HD_;
  const short* Kb = K + (size_t)(b * NKV_ + kvh) * S_ * HD_;
  const short* Vb = V + (size_t)(b * NKV_ + kvh) * S_ * HD_;

  const int vd = tid & 127, vg = tid >> 7;

  for (int half = 0; half < 2; ++half) {
    const int qt = (half == 0) ? pair : 31 - pair;
    const int q0w = qt * 64 + wave * 16;

    short8 qf[4];
#pragma unroll
    for (int kk = 0; kk < 4; ++kk)
      qf[kk] = *(const short8*)(Qb + (size_t)(q0w + lm) * HD_ + kk * 32 + kg * 8);

    float mrow[4], lrow[4];
    float4v o[8];
#pragma unroll
    for (int r = 0; r < 4; ++r) { mrow[r] = -1e9f; lrow[r] = 0.f; }
#pragma unroll
    for (int df = 0; df < 8; ++df) o[df] = (float4v){0.f, 0.f, 0.f, 0.f};

    const int ntiles = qt + 1;
    for (int j = 0; j < ntiles; ++j) {
      const int k0 = j * TK;
      short8 kv[4];
#pragma unroll
      for (int c = 0; c < 4; ++c) {
        int ch = tid + 256 * c;
        int row = ch >> 4, kc = ch & 15;
        kv[c] = *(const short8*)(Kb + (size_t)(k0 + row) * HD_ + kc * 8);
      }
      unsigned short vvv[4][8];
#pragma unroll
      for (int c = 0; c < 4; ++c) {
        int kc = vg * 4 + c;
#pragma unroll
        for (int jj = 0; jj < 8; ++jj)
          vvv[c][jj] = (unsigned short)Vb[(size_t)(k0 + kc * 8 + jj) * HD_ + vd];
      }
      __syncthreads();
#pragma unroll
      for (int c = 0; c < 4; ++c) {
        int ch = tid + 256 * c;
        int row = ch >> 4, kc = ch & 15;
        *(short8*)(sK + row * KP + kc * 8) = kv[c];
      }
#pragma unroll
      for (int c = 0; c < 4; ++c) {
        int kc = vg * 4 + c;
        short8 w;
#pragma unroll
        for (int jj = 0; jj < 8; ++jj) w[jj] = (short)vvv[c][jj];
        *(short8*)(sVt + vd * VP + kc * 8) = w;
      }
      __syncthreads();

      float4v sf[4];
#pragma unroll
      for (int nj = 0; nj < 4; ++nj) sf[nj] = (float4v){0.f, 0.f, 0.f, 0.f};
#pragma unroll
      for (int kk = 0; kk < 4; ++kk) {
        int kd = kk * 4 + kg;
#pragma unroll
        for (int nj = 0; nj < 4; ++nj) {
          short8 bf = *(const short8*)(sK + (nj * 16 + lm) * KP + kd * 8);
          sf[nj] = __builtin_amdgcn_mfma_f32_16x16x32_bf16(qf[kk], bf, sf[nj], 0, 0, 0);
        }
      }

      const float scale = 0.08838834764831845f;  // 1/sqrt(128)
      const bool diag = (j == qt);
#pragma unroll
      for (int r = 0; r < 4; ++r) {
        float pv[4];
        float mx = -3e38f;
        if (diag) {
          const int qloc = wave * 16 + kg * 4 + r;
#pragma unroll
          for (int nj = 0; nj < 4; ++nj) {
            float v = ((nj * 16 + lm) <= qloc) ? sf[nj][r] * scale : -3e38f;
            pv[nj] = v; mx = fmaxf(mx, v);
          }
        } else {
#pragma unroll
          for (int nj = 0; nj < 4; ++nj) {
            float v = sf[nj][r] * scale;
            pv[nj] = v; mx = fmaxf(mx, v);
          }
        }
        mx = fmaxf(mx, __shfl_xor(mx, 1, 64));
        mx = fmaxf(mx, __shfl_xor(mx, 2, 64));
        mx = fmaxf(mx, __shfl_xor(mx, 4, 64));
        mx = fmaxf(mx, __shfl_xor(mx, 8, 64));
        float mold = mrow[r];
        float mnew = fmaxf(mold, mx);
        float alpha = __expf(fminf(mold - mnew, 0.f));
        float rs = 0.f;
#pragma unroll
        for (int nj = 0; nj < 4; ++nj) {
          float e = __expf(fminf(pv[nj] - mnew, 0.f));
          rs += e;
          sP[(wave * 16 + kg * 4 + r) * VP + nj * 16 + lm] = f2bf(e);
        }
        rs += __shfl_xor(rs, 1, 64);
        rs += __shfl_xor(rs, 2, 64);
        rs += __shfl_xor(rs, 4, 64);
        rs += __shfl_xor(rs, 8, 64);
        mrow[r] = mnew;
        lrow[r] = lrow[r] * alpha + rs;
#pragma unroll
        for (int df = 0; df < 8; ++df) o[df][r] *= alpha;
      }

#pragma unroll
      for (int kst = 0; kst < 2; ++kst) {
        short8 pa = *(const short8*)(sP + (wave * 16 + lm) * VP + kst * 32 + kg * 8);
#pragma unroll
        for (int df = 0; df < 8; ++df) {
          short8 vf = *(const short8*)(sVt + (df * 16 + lm) * VP + kst * 32 + kg * 8);
          o[df] = __builtin_amdgcn_mfma_f32_16x16x32_bf16(pa, vf, o[df], 0, 0, 0);
        }
      }
    }

#pragma unroll
    for (int r = 0; r < 4; ++r) {
      float inv = 1.f / lrow[r];
      const size_t rowoff =
          (size_t)(b * S_ + q0w + kg * 4 + r) * QDIM_ + h * HD_;
#pragma unroll
      for (int df = 0; df < 8; ++df)
        O[rowoff + df * 16 + lm] = f2bf(o[df][r] * inv);
    }
  }
}

// ---------------------------------------------------------------------------
extern "C" void kernel_launch(void* const* d_in, const int* in_sizes, int n_in,
                              void* d_out, int out_size, void* d_ws, size_t ws_size,
                              hipStream_t stream) {
  const float* x     = (const float*)d_in[0];  // [B,S,D] fp32
  const float* freqs = (const float*)d_in[1];  // [S,HD] fp32
  const float* Wqkv  = (const float*)d_in[2];  // [3072,2048] fp32
  const float* Wo    = (const float*)d_in[3];  // [2048,2048] fp32
  float* out = (float*)d_out;                  // [B,S,D] fp32

  // ws layout (bf16 shorts), stream-ordered aliases:
  //   xb (dead after GEMM1)  <- Wob (converted after GEMM1)
  //   xqkv (dead after rope) <- attn
  short* ws     = (short*)d_ws;
  short* xb     = ws;                                    // 4096*2048 = 8.39M
  short* Wob    = ws;                                    // 2048*2048 = 4.19M (alias xb)
  short* Wqkvb  = ws + (size_t)4096 * 2048;              // 3072*2048 = 6.29M
  short* xqkv   = Wqkvb + (size_t)QKV_ * 2048;           // 4096*3072 = 12.58M
  short* attn   = xqkv;                                  // 4096*2048 (alias)
  short* Qr     = xqkv + (size_t)4096 * QKV_;            // 8.39M
  short* Kr     = Qr + (size_t)B_ * NH_ * S_ * HD_;      // 2.10M
  short* Vv     = Kr + (size_t)B_ * NKV_ * S_ * HD_;     // 2.10M
  // total 39.84M shorts = 79.7 MB

  f32_to_bf16<<<(4096 * 2048 / 8) / 256, 256, 0, stream>>>(x, xb, 4096 * 2048 / 8);
  f32_to_bf16<<<(QKV_ * 2048 / 8) / 256, 256, 0, stream>>>(Wqkv, Wqkvb, QKV_ * 2048 / 8);
  gemm_nt_bf16<QKV_, 2048, false>
      <<<dim3(QKV_ / 128, 4096 / 128), 256, 0, stream>>>(xb, Wqkvb, xqkv);
  f32_to_bf16<<<(2048 * 2048 / 8) / 256, 256, 0, stream>>>(Wo, Wob, 2048 * 2048 / 8);
  rope_split<<<(B_ * S_ * QKV_ / 8) / 256, 256, 0, stream>>>(xqkv, freqs, Qr, Kr, Vv);
  attn_causal<<<dim3(16, B_ * NH_), 256, 0, stream>>>(Qr, Kr, Vv, attn);
  gemm_nt_bf16<2048, 2048, true>
      <<<dim3(2048 / 128, 4096 / 128), 256, 0, stream>>>(attn, Wob, out);
}

// Round 6
// 337.611 us; speedup vs baseline: 1.6014x; 1.0377x over previous
//
#include <hip/hip_runtime.h>
#include <hip/hip_bf16.h>
#include <cstdint>
#include <cstddef>

#define B_ 2
#define S_ 2048
#define NH_ 16
#define NKV_ 4
#define HD_ 128
#define QDIM_ 2048
#define KVDIM_ 512
#define QKV_ 3072

typedef __attribute__((ext_vector_type(8))) short short8;
typedef __attribute__((ext_vector_type(4))) float float4v;

__device__ __forceinline__ float bf2f(short u) {
  union { unsigned int i; float f; } v;
  v.i = ((unsigned int)(unsigned short)u) << 16;
  return v.f;
}
__device__ __forceinline__ short f2bf(float f) {
  union { float f; unsigned int i; } v; v.f = f;
  unsigned int x = v.i;
  x += 0x7fffu + ((x >> 16) & 1u);   // RNE
  return (short)(x >> 16);
}

__device__ __forceinline__ void async_copy16(void* lds, const void* g) {
  __builtin_amdgcn_global_load_lds(
      (const __attribute__((address_space(1))) void*)g,
      (__attribute__((address_space(3))) void*)lds, 16, 0, 0);
}

// ---------------------------------------------------------------------------
// fp32 -> bf16 convert (HBM-bound). n8 = element count / 8.
// ---------------------------------------------------------------------------
__global__ void f32_to_bf16(const float* __restrict__ src, short* __restrict__ dst,
                            int n8) {
  int id = blockIdx.x * 256 + threadIdx.x;
  if (id >= n8) return;
  const float* f = src + (size_t)id * 8;
  float4v a = *(const float4v*)(f);
  float4v b = *(const float4v*)(f + 4);
  short8 r;
#pragma unroll
  for (int e = 0; e < 4; ++e) { r[e] = f2bf(a[e]); r[4 + e] = f2bf(b[e]); }
  *(short8*)(dst + (size_t)id * 8) = r;
}

// ---------------------------------------------------------------------------
// NT GEMM, pure bf16 operands (unchanged from round 5 — shape-plateau ~190us
// combined; revisit after attention).
// ---------------------------------------------------------------------------
template <int N, int K, bool CF32>
__global__ __launch_bounds__(256)
void gemm_nt_bf16(const short* __restrict__ A, const short* __restrict__ Bm,
                  void* __restrict__ Cp) {
  __shared__ __align__(16) short sA[128 * 32];
  __shared__ __align__(16) short sB[128 * 32];
  const int tid = threadIdx.x;
  const int m0 = blockIdx.y * 128, n0 = blockIdx.x * 128;
  const int wave = tid >> 6, lane = tid & 63;
  const int wm = (wave & 1) << 6, wn = (wave >> 1) << 6;
  const int lm = lane & 15, kg = lane >> 4;

  float4v acc[4][4];
#pragma unroll
  for (int i = 0; i < 4; ++i)
#pragma unroll
    for (int j = 0; j < 4; ++j)
      acc[i][j] = (float4v){0.f, 0.f, 0.f, 0.f};

  const int r0 = tid >> 2, c0 = tid & 3;
  const short* gA0 = A + (size_t)(m0 + r0) * K + c0 * 8;
  const short* gA1 = gA0 + (size_t)64 * K;
  const short* gB0 = Bm + (size_t)(n0 + r0) * K + c0 * 8;
  const short* gB1 = gB0 + (size_t)64 * K;
  short* lA0 = sA + tid * 8;
  short* lA1 = sA + 2048 + tid * 8;
  short* lB0 = sB + tid * 8;
  short* lB1 = sB + 2048 + tid * 8;

  for (int k0 = 0; k0 < K; k0 += 32) {
    async_copy16(lA0, gA0 + k0);
    async_copy16(lA1, gA1 + k0);
    async_copy16(lB0, gB0 + k0);
    async_copy16(lB1, gB1 + k0);
    __syncthreads();

    short8 a[4], b[4];
#pragma unroll
    for (int i = 0; i < 4; ++i)
      a[i] = *(const short8*)(sA + (wm + i * 16 + lm) * 32 + kg * 8);
#pragma unroll
    for (int j = 0; j < 4; ++j)
      b[j] = *(const short8*)(sB + (wn + j * 16 + lm) * 32 + kg * 8);
#pragma unroll
    for (int i = 0; i < 4; ++i)
#pragma unroll
      for (int j = 0; j < 4; ++j)
        acc[i][j] = __builtin_amdgcn_mfma_f32_16x16x32_bf16(a[i], b[j], acc[i][j], 0, 0, 0);
    __syncthreads();
  }

#pragma unroll
  for (int i = 0; i < 4; ++i) {
    const int rb = m0 + wm + i * 16 + kg * 4;
#pragma unroll
    for (int j = 0; j < 4; ++j) {
      const int cc = n0 + wn + j * 16 + lm;
#pragma unroll
      for (int r = 0; r < 4; ++r) {
        if constexpr (CF32)
          ((float*)Cp)[(size_t)(rb + r) * N + cc] = acc[i][j][r];
        else
          ((short*)Cp)[(size_t)(rb + r) * N + cc] = f2bf(acc[i][j][r]);
      }
    }
  }
}

// ---------------------------------------------------------------------------
// RoPE + split/layout. Q outputs are pre-scaled by 1/sqrt(HD) (folded out of
// the attention softmax).
// ---------------------------------------------------------------------------
__global__ void rope_split(const short* __restrict__ xqkv, const float* __restrict__ freqs,
                           short* __restrict__ Qr, short* __restrict__ Kr,
                           short* __restrict__ Vv) {
  const int id = blockIdx.x * 256 + threadIdx.x;
  const int i = id / (QKV_ / 8);   // token 0..4095
  const int c8 = id % (QKV_ / 8);
  const int col = c8 * 8;
  const int b = i >> 11, s = i & (S_ - 1);
  short8 xv = *(const short8*)(xqkv + (size_t)i * QKV_ + col);
  if (col < QDIM_ + KVDIM_) {
    int d;
    short* dst;
    float sc;
    if (col < QDIM_) {
      int hh = col >> 7; d = col & 127;
      dst = Qr + ((size_t)(b * NH_ + hh) * S_ + s) * HD_ + d;
      sc = 0.08838834764831845f;   // 1/sqrt(128)
    } else {
      int cc = col - QDIM_;
      int hh = cc >> 7; d = cc & 127;
      dst = Kr + ((size_t)(b * NKV_ + hh) * S_ + s) * HD_ + d;
      sc = 1.0f;
    }
    const float* fp = freqs + (size_t)s * HD_ + d;
    float4v fa = *(const float4v*)(fp);
    float4v fb = *(const float4v*)(fp + 4);
    float ff[8] = {fa[0], fa[1], fa[2], fa[3], fb[0], fb[1], fb[2], fb[3]};
    short8 ov;
#pragma unroll
    for (int pp = 0; pp < 4; ++pp) {
      float t0 = bf2f(xv[2 * pp]), t1 = bf2f(xv[2 * pp + 1]);
      float f0 = ff[2 * pp], f1 = ff[2 * pp + 1];
      ov[2 * pp]     = f2bf((t0 * f1 - t1 * f0) * sc);
      ov[2 * pp + 1] = f2bf((t0 * f0 + t1 * f1) * sc);
    }
    *(short8*)dst = ov;
  } else {
    int cc = col - QDIM_ - KVDIM_;
    int hh = cc >> 7, d = cc & 127;
    *(short8*)(Vv + ((size_t)(b * NKV_ + hh) * S_ + s) * HD_ + d) = xv;
  }
}

// ---------------------------------------------------------------------------
// V transpose: Vv [b][kvh][s][d] -> Vt [b][kvh][d][s]. LDS-tiled 64x64.
// ---------------------------------------------------------------------------
__global__ void transpose_v(const short* __restrict__ Vv, short* __restrict__ Vt) {
  __shared__ short t[64][72];
  const int s0 = blockIdx.x * 64, d0 = blockIdx.y * 64;
  const short* src = Vv + (size_t)blockIdx.z * S_ * HD_;
  short* dst = Vt + (size_t)blockIdx.z * S_ * HD_;
  const int tid = threadIdx.x;
#pragma unroll
  for (int c = 0; c < 2; ++c) {
    int ch = tid + 256 * c;
    int row = ch >> 3, kc = ch & 7;
    *(short8*)(&t[row][kc * 8]) =
        *(const short8*)(src + (size_t)(s0 + row) * HD_ + d0 + kc * 8);
  }
  __syncthreads();
#pragma unroll
  for (int c = 0; c < 2; ++c) {
    int ch = tid + 256 * c;
    int drow = ch >> 3, sc = ch & 7;
    short8 w;
#pragma unroll
    for (int j = 0; j < 8; ++j) w[j] = t[sc * 8 + j][drow];
    *(short8*)(dst + (size_t)(d0 + drow) * S_ + s0 + sc * 8) = w;
  }
}

// ---------------------------------------------------------------------------
// Flash attention v3. TQ=64 paired (i, 31-i); K and V^T staged via
// global_load_lds width=16 into unpadded LDS with XOR chunk swizzle
// (pos kc holds data chunk kc^(row&7); read chunk kd at kd^(n&7)).
// Q pre-scaled by 1/sqrt(HD) in rope_split.
// ---------------------------------------------------------------------------
#define TK 64
#define VP 72

__global__ __launch_bounds__(256)
void attn_causal(const short* __restrict__ Q, const short* __restrict__ K,
                 const short* __restrict__ Vt, short* __restrict__ O) {
  const int pair = blockIdx.x;   // 0..15
  const int bh = blockIdx.y;     // 0..31
  const int b = bh >> 4, h = bh & 15;
  const int kvh = h >> 2;
  const int tid = threadIdx.x, wave = tid >> 6, lane = tid & 63;
  const int lm = lane & 15, kg = lane >> 4;

  __shared__ __align__(16) short sK[TK * HD_];    // [64][128] swizzled, 16KB
  __shared__ __align__(16) short sVt[HD_ * TK];   // [128][64] swizzled, 16KB
  __shared__ __align__(16) short sP[64 * VP];     // [64][64+8], 9.2KB

  const short* Qb = Q + (size_t)(b * NH_ + h) * S_ * HD_;
  const short* Kb = K + (size_t)(b * NKV_ + kvh) * S_ * HD_;
  const short* Vtb = Vt + (size_t)(b * NKV_ + kvh) * S_ * HD_;

  // staging assignments (chunk = tid + 256*c; LDS dest = base + chunk*16B,
  // lane-consecutive within wave as global_load_lds requires)
  const int krow0 = tid >> 4, kkc0 = tid & 15;    // K: 1024 chunks, 16/row
  const int vrow0 = tid >> 3, vkc0 = tid & 7;     // Vt: 1024 chunks, 8/row

  for (int half = 0; half < 2; ++half) {
    const int qt = (half == 0) ? pair : 31 - pair;
    const int q0w = qt * 64 + wave * 16;

    short8 qf[4];
#pragma unroll
    for (int kk = 0; kk < 4; ++kk)
      qf[kk] = *(const short8*)(Qb + (size_t)(q0w + lm) * HD_ + kk * 32 + kg * 8);

    float mrow[4], lrow[4];
    float4v o[8];
#pragma unroll
    for (int r = 0; r < 4; ++r) { mrow[r] = -1e9f; lrow[r] = 0.f; }
#pragma unroll
    for (int df = 0; df < 8; ++df) o[df] = (float4v){0.f, 0.f, 0.f, 0.f};

    const int ntiles = qt + 1;
    for (int j = 0; j < ntiles; ++j) {
      const int k0 = j * TK;
      // K stage: position (row, kc) holds global chunk kc^(row&7)
#pragma unroll
      for (int c = 0; c < 4; ++c) {
        int ch = tid + 256 * c;
        int row = (c & 1) ? (krow0 + 16 * (c >> 0)) : krow0;  // see below
        (void)row;
      }
      // (explicit per-c rows to keep addressing simple)
#pragma unroll
      for (int c = 0; c < 4; ++c) {
        int ch = tid + 256 * c;
        int row = ch >> 4, kc = ch & 15;
        async_copy16(sK + ch * 8,
                     Kb + (size_t)(k0 + row) * HD_ + (kc ^ (row & 7)) * 8);
      }
      // Vt stage: row = d (0..127), 8 chunks of 8 along k
#pragma unroll
      for (int c = 0; c < 4; ++c) {
        int ch = tid + 256 * c;
        int row = ch >> 3, kc = ch & 7;
        async_copy16(sVt + ch * 8,
                     Vtb + (size_t)row * S_ + k0 + (kc ^ (row & 7)) * 8);
      }
      __syncthreads();   // drains vmcnt before LDS reads

      // S = Q K^T (4 k-steps over HD=128)
      float4v sf[4];
#pragma unroll
      for (int nj = 0; nj < 4; ++nj) sf[nj] = (float4v){0.f, 0.f, 0.f, 0.f};
#pragma unroll
      for (int kk = 0; kk < 4; ++kk) {
        int kd = kk * 4 + kg;
#pragma unroll
        for (int nj = 0; nj < 4; ++nj) {
          int n = nj * 16 + lm;
          short8 bf = *(const short8*)(sK + n * HD_ + (kd ^ (n & 7)) * 8);
          sf[nj] = __builtin_amdgcn_mfma_f32_16x16x32_bf16(qf[kk], bf, sf[nj], 0, 0, 0);
        }
      }

      // online softmax (Q pre-scaled; rows kg*4+r, cols nj*16+lm)
      const bool diag = (j == qt);
#pragma unroll
      for (int r = 0; r < 4; ++r) {
        float pv[4];
        float mx = -3e38f;
        if (diag) {
          const int qloc = wave * 16 + kg * 4 + r;
#pragma unroll
          for (int nj = 0; nj < 4; ++nj) {
            float v = ((nj * 16 + lm) <= qloc) ? sf[nj][r] : -3e38f;
            pv[nj] = v; mx = fmaxf(mx, v);
          }
        } else {
#pragma unroll
          for (int nj = 0; nj < 4; ++nj) {
            float v = sf[nj][r];
            pv[nj] = v; mx = fmaxf(mx, v);
          }
        }
        mx = fmaxf(mx, __shfl_xor(mx, 1, 64));
        mx = fmaxf(mx, __shfl_xor(mx, 2, 64));
        mx = fmaxf(mx, __shfl_xor(mx, 4, 64));
        mx = fmaxf(mx, __shfl_xor(mx, 8, 64));
        float mold = mrow[r];
        float mnew = fmaxf(mold, mx);
        float alpha = __expf(fminf(mold - mnew, 0.f));
        float rs = 0.f;
#pragma unroll
        for (int nj = 0; nj < 4; ++nj) {
          float e = __expf(fminf(pv[nj] - mnew, 0.f));
          rs += e;
          sP[(wave * 16 + kg * 4 + r) * VP + nj * 16 + lm] = f2bf(e);
        }
        rs += __shfl_xor(rs, 1, 64);
        rs += __shfl_xor(rs, 2, 64);
        rs += __shfl_xor(rs, 4, 64);
        rs += __shfl_xor(rs, 8, 64);
        mrow[r] = mnew;
        lrow[r] = lrow[r] * alpha + rs;
#pragma unroll
        for (int df = 0; df < 8; ++df) o[df][r] *= alpha;
      }
      // sP rows are wave-private: no barrier between sP write and PV read.

      // O += P V (2 k-steps over TK=64); Vt B-frag: row n=d, chunk kst*4+kg
#pragma unroll
      for (int kst = 0; kst < 2; ++kst) {
        short8 pa = *(const short8*)(sP + (wave * 16 + lm) * VP + kst * 32 + kg * 8);
        int kd = kst * 4 + kg;
#pragma unroll
        for (int df = 0; df < 8; ++df) {
          int n = df * 16 + lm;
          short8 vf = *(const short8*)(sVt + n * TK + (kd ^ (n & 7)) * 8);
          o[df] = __builtin_amdgcn_mfma_f32_16x16x32_bf16(pa, vf, o[df], 0, 0, 0);
        }
      }
      __syncthreads();   // LDS reads done before next tile restages
    }

#pragma unroll
    for (int r = 0; r < 4; ++r) {
      float inv = 1.f / lrow[r];
      const size_t rowoff =
          (size_t)(b * S_ + q0w + kg * 4 + r) * QDIM_ + h * HD_;
#pragma unroll
      for (int df = 0; df < 8; ++df)
        O[rowoff + df * 16 + lm] = f2bf(o[df][r] * inv);
    }
  }
}

// ---------------------------------------------------------------------------
extern "C" void kernel_launch(void* const* d_in, const int* in_sizes, int n_in,
                              void* d_out, int out_size, void* d_ws, size_t ws_size,
                              hipStream_t stream) {
  const float* x     = (const float*)d_in[0];  // [B,S,D] fp32
  const float* freqs = (const float*)d_in[1];  // [S,HD] fp32
  const float* Wqkv  = (const float*)d_in[2];  // [3072,2048] fp32
  const float* Wo    = (const float*)d_in[3];  // [2048,2048] fp32
  float* out = (float*)d_out;                  // [B,S,D] fp32

  // ws layout (bf16 shorts), stream-ordered aliases:
  //   xb (dead after GEMM1)  <- Wob ; xqkv (dead after rope) <- attn
  short* ws     = (short*)d_ws;
  short* xb     = ws;                                    // 4096*2048
  short* Wob    = ws;                                    // 2048*2048 (alias xb)
  short* Wqkvb  = ws + (size_t)4096 * 2048;              // 3072*2048
  short* xqkv   = Wqkvb + (size_t)QKV_ * 2048;           // 4096*3072
  short* attn   = xqkv;                                  // 4096*2048 (alias)
  short* Qr     = xqkv + (size_t)4096 * QKV_;            // 8.39M
  short* Kr     = Qr + (size_t)B_ * NH_ * S_ * HD_;      // 2.10M
  short* Vv     = Kr + (size_t)B_ * NKV_ * S_ * HD_;     // 2.10M
  short* Vtg    = Vv + (size_t)B_ * NKV_ * S_ * HD_;     // 2.10M
  // total ~41.9M shorts = 83.9 MB

  f32_to_bf16<<<(4096 * 2048 / 8) / 256, 256, 0, stream>>>(x, xb, 4096 * 2048 / 8);
  f32_to_bf16<<<(QKV_ * 2048 / 8) / 256, 256, 0, stream>>>(Wqkv, Wqkvb, QKV_ * 2048 / 8);
  gemm_nt_bf16<QKV_, 2048, false>
      <<<dim3(QKV_ / 128, 4096 / 128), 256, 0, stream>>>(xb, Wqkvb, xqkv);
  f32_to_bf16<<<(2048 * 2048 / 8) / 256, 256, 0, stream>>>(Wo, Wob, 2048 * 2048 / 8);
  rope_split<<<(B_ * S_ * QKV_ / 8) / 256, 256, 0, stream>>>(xqkv, freqs, Qr, Kr, Vv);
  transpose_v<<<dim3(S_ / 64, HD_ / 64, B_ * NKV_), 256, 0, stream>>>(Vv, Vtg);
  attn_causal<<<dim3(16, B_ * NH_), 256, 0, stream>>>(Qr, Kr, Vtg, attn);
  gemm_nt_bf16<2048, 2048, true>
      <<<dim3(2048 / 128, 4096 / 128), 256, 0, stream>>>(attn, Wob, out);
}

// Round 8
// 328.665 us; speedup vs baseline: 1.6450x; 1.0272x over previous
//
#include <hip/hip_runtime.h>
#include <hip/hip_bf16.h>
#include <cstdint>
#include <cstddef>

#define B_ 2
#define S_ 2048
#define NH_ 16
#define NKV_ 4
#define HD_ 128
#define QDIM_ 2048
#define KVDIM_ 512
#define QKV_ 3072

typedef __attribute__((ext_vector_type(8))) short short8;
typedef __attribute__((ext_vector_type(4))) short bhalf4;   // renamed: short4 collides with HIP
typedef __attribute__((ext_vector_type(4))) float float4v;

__device__ __forceinline__ float bf2f(short u) {
  union { unsigned int i; float f; } v;
  v.i = ((unsigned int)(unsigned short)u) << 16;
  return v.f;
}
__device__ __forceinline__ short f2bf(float f) {
  union { float f; unsigned int i; } v; v.f = f;
  unsigned int x = v.i;
  x += 0x7fffu + ((x >> 16) & 1u);   // RNE
  return (short)(x >> 16);
}

__device__ __forceinline__ void async_copy16(void* lds, const void* g) {
  __builtin_amdgcn_global_load_lds(
      (const __attribute__((address_space(1))) void*)g,
      (__attribute__((address_space(3))) void*)lds, 16, 0, 0);
}

// ---------------------------------------------------------------------------
// fp32 -> bf16 convert (HBM-bound). n8 = element count / 8.
// ---------------------------------------------------------------------------
__global__ void f32_to_bf16(const float* __restrict__ src, short* __restrict__ dst,
                            int n8) {
  int id = blockIdx.x * 256 + threadIdx.x;
  if (id >= n8) return;
  const float* f = src + (size_t)id * 8;
  float4v a = *(const float4v*)(f);
  float4v b = *(const float4v*)(f + 4);
  short8 r;
#pragma unroll
  for (int e = 0; e < 4; ++e) { r[e] = f2bf(a[e]); r[4 + e] = f2bf(b[e]); }
  *(short8*)(dst + (size_t)id * 8) = r;
}

// ---------------------------------------------------------------------------
// NT GEMM, pure bf16 operands (unchanged — shape plateau; attn first).
// ---------------------------------------------------------------------------
template <int N, int K, bool CF32>
__global__ __launch_bounds__(256)
void gemm_nt_bf16(const short* __restrict__ A, const short* __restrict__ Bm,
                  void* __restrict__ Cp) {
  __shared__ __align__(16) short sA[128 * 32];
  __shared__ __align__(16) short sB[128 * 32];
  const int tid = threadIdx.x;
  const int m0 = blockIdx.y * 128, n0 = blockIdx.x * 128;
  const int wave = tid >> 6, lane = tid & 63;
  const int wm = (wave & 1) << 6, wn = (wave >> 1) << 6;
  const int lm = lane & 15, kg = lane >> 4;

  float4v acc[4][4];
#pragma unroll
  for (int i = 0; i < 4; ++i)
#pragma unroll
    for (int j = 0; j < 4; ++j)
      acc[i][j] = (float4v){0.f, 0.f, 0.f, 0.f};

  const int r0 = tid >> 2, c0 = tid & 3;
  const short* gA0 = A + (size_t)(m0 + r0) * K + c0 * 8;
  const short* gA1 = gA0 + (size_t)64 * K;
  const short* gB0 = Bm + (size_t)(n0 + r0) * K + c0 * 8;
  const short* gB1 = gB0 + (size_t)64 * K;
  short* lA0 = sA + tid * 8;
  short* lA1 = sA + 2048 + tid * 8;
  short* lB0 = sB + tid * 8;
  short* lB1 = sB + 2048 + tid * 8;

  for (int k0 = 0; k0 < K; k0 += 32) {
    async_copy16(lA0, gA0 + k0);
    async_copy16(lA1, gA1 + k0);
    async_copy16(lB0, gB0 + k0);
    async_copy16(lB1, gB1 + k0);
    __syncthreads();

    short8 a[4], b[4];
#pragma unroll
    for (int i = 0; i < 4; ++i)
      a[i] = *(const short8*)(sA + (wm + i * 16 + lm) * 32 + kg * 8);
#pragma unroll
    for (int j = 0; j < 4; ++j)
      b[j] = *(const short8*)(sB + (wn + j * 16 + lm) * 32 + kg * 8);
#pragma unroll
    for (int i = 0; i < 4; ++i)
#pragma unroll
      for (int j = 0; j < 4; ++j)
        acc[i][j] = __builtin_amdgcn_mfma_f32_16x16x32_bf16(a[i], b[j], acc[i][j], 0, 0, 0);
    __syncthreads();
  }

#pragma unroll
  for (int i = 0; i < 4; ++i) {
    const int rb = m0 + wm + i * 16 + kg * 4;
#pragma unroll
    for (int j = 0; j < 4; ++j) {
      const int cc = n0 + wn + j * 16 + lm;
#pragma unroll
      for (int r = 0; r < 4; ++r) {
        if constexpr (CF32)
          ((float*)Cp)[(size_t)(rb + r) * N + cc] = acc[i][j][r];
        else
          ((short*)Cp)[(size_t)(rb + r) * N + cc] = f2bf(acc[i][j][r]);
      }
    }
  }
}

// ---------------------------------------------------------------------------
// RoPE + split/layout; Q pre-scaled by 1/sqrt(HD).
// ---------------------------------------------------------------------------
__global__ void rope_split(const short* __restrict__ xqkv, const float* __restrict__ freqs,
                           short* __restrict__ Qr, short* __restrict__ Kr,
                           short* __restrict__ Vv) {
  const int id = blockIdx.x * 256 + threadIdx.x;
  const int i = id / (QKV_ / 8);   // token 0..4095
  const int c8 = id % (QKV_ / 8);
  const int col = c8 * 8;
  const int b = i >> 11, s = i & (S_ - 1);
  short8 xv = *(const short8*)(xqkv + (size_t)i * QKV_ + col);
  if (col < QDIM_ + KVDIM_) {
    int d;
    short* dst;
    float sc;
    if (col < QDIM_) {
      int hh = col >> 7; d = col & 127;
      dst = Qr + ((size_t)(b * NH_ + hh) * S_ + s) * HD_ + d;
      sc = 0.08838834764831845f;   // 1/sqrt(128)
    } else {
      int cc = col - QDIM_;
      int hh = cc >> 7; d = cc & 127;
      dst = Kr + ((size_t)(b * NKV_ + hh) * S_ + s) * HD_ + d;
      sc = 1.0f;
    }
    const float* fp = freqs + (size_t)s * HD_ + d;
    float4v fa = *(const float4v*)(fp);
    float4v fb = *(const float4v*)(fp + 4);
    float ff[8] = {fa[0], fa[1], fa[2], fa[3], fb[0], fb[1], fb[2], fb[3]};
    short8 ov;
#pragma unroll
    for (int pp = 0; pp < 4; ++pp) {
      float t0 = bf2f(xv[2 * pp]), t1 = bf2f(xv[2 * pp + 1]);
      float f0 = ff[2 * pp], f1 = ff[2 * pp + 1];
      ov[2 * pp]     = f2bf((t0 * f1 - t1 * f0) * sc);
      ov[2 * pp + 1] = f2bf((t0 * f0 + t1 * f1) * sc);
    }
    *(short8*)dst = ov;
  } else {
    int cc = col - QDIM_ - KVDIM_;
    int hh = cc >> 7, d = cc & 127;
    *(short8*)(Vv + ((size_t)(b * NKV_ + hh) * S_ + s) * HD_ + d) = xv;
  }
}

// ---------------------------------------------------------------------------
// V transpose: Vv [b][kvh][s][d] -> Vt [b][kvh][d][s]. LDS-tiled 64x64.
// ---------------------------------------------------------------------------
__global__ void transpose_v(const short* __restrict__ Vv, short* __restrict__ Vt) {
  __shared__ short t[64][72];
  const int s0 = blockIdx.x * 64, d0 = blockIdx.y * 64;
  const short* src = Vv + (size_t)blockIdx.z * S_ * HD_;
  short* dst = Vt + (size_t)blockIdx.z * S_ * HD_;
  const int tid = threadIdx.x;
#pragma unroll
  for (int c = 0; c < 2; ++c) {
    int ch = tid + 256 * c;
    int row = ch >> 3, kc = ch & 7;
    *(short8*)(&t[row][kc * 8]) =
        *(const short8*)(src + (size_t)(s0 + row) * HD_ + d0 + kc * 8);
  }
  __syncthreads();
#pragma unroll
  for (int c = 0; c < 2; ++c) {
    int ch = tid + 256 * c;
    int drow = ch >> 3, sc = ch & 7;
    short8 w;
#pragma unroll
    for (int j = 0; j < 8; ++j) w[j] = t[sc * 8 + j][drow];
    *(short8*)(dst + (size_t)(d0 + drow) * S_ + s0 + sc * 8) = w;
  }
}

// ---------------------------------------------------------------------------
// Flash attention v4: S^T formulation. TQ=64 paired (i,31-i); each lane owns
// ONE q column (q=lane&15) -> softmax reductions are 15 local ops + 2
// shuffles; P exits QK^T already in the B-layout of mfma_16x16x16bf16_1k, so
// the sP LDS round-trip is gone. O accumulates as O^T; LDS transpose at
// epilogue (dedicated sO, wave-private). K/Vt staged async with XOR swizzle.
// ---------------------------------------------------------------------------
#define TK 64

__global__ __launch_bounds__(256)
void attn_causal(const short* __restrict__ Q, const short* __restrict__ K,
                 const short* __restrict__ Vt, short* __restrict__ O) {
  const int pair = blockIdx.x;   // 0..15
  const int bh = blockIdx.y;     // 0..31
  const int b = bh >> 4, h = bh & 15;
  const int kvh = h >> 2;
  const int tid = threadIdx.x, wave = tid >> 6, lane = tid & 63;
  const int lm = lane & 15, kg = lane >> 4;

  __shared__ __align__(16) short sK[TK * HD_];    // [64][128] swizzled, 16KB
  __shared__ __align__(16) short sVt[HD_ * TK];   // [128][64] swizzled, 16KB
  __shared__ __align__(16) short sO[4 * 16 * 128];// per-wave O^T scratch, 16KB

  const short* Qb = Q + (size_t)(b * NH_ + h) * S_ * HD_;
  const short* Kb = K + (size_t)(b * NKV_ + kvh) * S_ * HD_;
  const short* Vtb = Vt + (size_t)(b * NKV_ + kvh) * S_ * HD_;

  for (int half = 0; half < 2; ++half) {
    const int qt = (half == 0) ? pair : 31 - pair;
    const int q0w = qt * 64 + wave * 16;
    const int qglob = q0w + lm;     // this lane's q row

    // Q fragments: B[n=lane&15][k=kg*8+j] == A-layout -> same loads as before
    short8 qf[4];
#pragma unroll
    for (int kk = 0; kk < 4; ++kk)
      qf[kk] = *(const short8*)(Qb + (size_t)qglob * HD_ + kk * 32 + kg * 8);

    float mcur = -1e9f, lcur = 0.f;
    float4v o[8];                   // O^T[d=df*16+kg*4+r][q=lm]
#pragma unroll
    for (int df = 0; df < 8; ++df) o[df] = (float4v){0.f, 0.f, 0.f, 0.f};

    const int ntiles = qt + 1;
    for (int j = 0; j < ntiles; ++j) {
      const int k0 = j * TK;
      // K stage: pos (row, kc) holds chunk kc^(row&7)
#pragma unroll
      for (int c = 0; c < 4; ++c) {
        int ch = tid + 256 * c;
        int row = ch >> 4, kc = ch & 15;
        async_copy16(sK + ch * 8,
                     Kb + (size_t)(k0 + row) * HD_ + (kc ^ (row & 7)) * 8);
      }
      // Vt stage: row = d, 8 chunks along k
#pragma unroll
      for (int c = 0; c < 4; ++c) {
        int ch = tid + 256 * c;
        int row = ch >> 3, kc = ch & 7;
        async_copy16(sVt + ch * 8,
                     Vtb + (size_t)row * S_ + k0 + (kc ^ (row & 7)) * 8);
      }
      __syncthreads();   // drain global_load_lds before LDS reads

      // S^T = K * Q^T: A = K rows (m = kcol), B = Q rows (n = q)
      float4v sfT[4];
#pragma unroll
      for (int mj = 0; mj < 4; ++mj) sfT[mj] = (float4v){0.f, 0.f, 0.f, 0.f};
#pragma unroll
      for (int kk = 0; kk < 4; ++kk) {
        int kd = kk * 4 + kg;
#pragma unroll
        for (int mj = 0; mj < 4; ++mj) {
          int row = mj * 16 + lm;
          short8 af = *(const short8*)(sK + row * HD_ + (kd ^ (row & 7)) * 8);
          sfT[mj] = __builtin_amdgcn_mfma_f32_16x16x32_bf16(af, qf[kk], sfT[mj], 0, 0, 0);
        }
      }

      // causal mask (diagonal tile only): kcol = k0 + mj*16 + kg*4 + r
      if (j == qt) {
#pragma unroll
        for (int mj = 0; mj < 4; ++mj)
#pragma unroll
          for (int r = 0; r < 4; ++r) {
            int kcol = k0 + mj * 16 + kg * 4 + r;
            sfT[mj][r] = (kcol <= qglob) ? sfT[mj][r] : -3e38f;
          }
      }

      // online softmax for this lane's q column
      float mx = -3e38f;
#pragma unroll
      for (int mj = 0; mj < 4; ++mj)
#pragma unroll
        for (int r = 0; r < 4; ++r) mx = fmaxf(mx, sfT[mj][r]);
      mx = fmaxf(mx, __shfl_xor(mx, 16, 64));
      mx = fmaxf(mx, __shfl_xor(mx, 32, 64));
      float mnew = fmaxf(mcur, mx);
      float alpha = __expf(fminf(mcur - mnew, 0.f));
      float rs = 0.f;
      bhalf4 pb[4];   // P^T B-frags: B[n=q][k=t*16+kg*4+j]
#pragma unroll
      for (int t = 0; t < 4; ++t)
#pragma unroll
        for (int r = 0; r < 4; ++r) {
          float e = __expf(fminf(sfT[t][r] - mnew, 0.f));
          rs += e;
          pb[t][r] = f2bf(e);
        }
      rs += __shfl_xor(rs, 16, 64);
      rs += __shfl_xor(rs, 32, 64);
      mcur = mnew;
      lcur = lcur * alpha + rs;
#pragma unroll
      for (int df = 0; df < 8; ++df)
#pragma unroll
        for (int r = 0; r < 4; ++r) o[df][r] *= alpha;

      // O^T += V^T * P^T  (x16 MFMA, 4 k-chunks of 16)
#pragma unroll
      for (int t = 0; t < 4; ++t) {
        int kc = t * 2 + (kg >> 1);
#pragma unroll
        for (int df = 0; df < 8; ++df) {
          int row = df * 16 + lm;
          bhalf4 va = *(const bhalf4*)(sVt + row * TK + (kc ^ (row & 7)) * 8 +
                                       (kg & 1) * 4);
          o[df] = __builtin_amdgcn_mfma_f32_16x16x16bf16_1k(va, pb[t], o[df], 0, 0, 0);
        }
      }
      __syncthreads();   // LDS reads done before next tile restages
    }

    // epilogue: divide by l, transpose via wave-private sO, coalesced store
    float inv = 1.f / lcur;
    short* myO = sO + wave * 2048;   // [16 q][128 d]
#pragma unroll
    for (int df = 0; df < 8; ++df) {
      unsigned int p0 = (unsigned short)f2bf(o[df][0] * inv) |
                        ((unsigned int)(unsigned short)f2bf(o[df][1] * inv) << 16);
      unsigned int p1 = (unsigned short)f2bf(o[df][2] * inv) |
                        ((unsigned int)(unsigned short)f2bf(o[df][3] * inv) << 16);
      int base = lm * 128 + df * 16 + kg * 4;
      *(unsigned int*)(myO + base) = p0;
      *(unsigned int*)(myO + base + 2) = p1;
    }
    // wave-private: no barrier; compiler orders via lgkmcnt
    int q = lane >> 2, dp = (lane & 3) * 32;
    const size_t rowoff = (size_t)(b * S_ + q0w + q) * QDIM_ + h * HD_ + dp;
#pragma unroll
    for (int e = 0; e < 4; ++e) {
      short8 w = *(const short8*)(myO + q * 128 + dp + e * 8);
      *(short8*)(O + rowoff + e * 8) = w;
    }
    // next half's staging is safe: all sK/sVt reads completed at the last
    // in-loop barrier; epilogue touches only sO.
  }
}

// ---------------------------------------------------------------------------
extern "C" void kernel_launch(void* const* d_in, const int* in_sizes, int n_in,
                              void* d_out, int out_size, void* d_ws, size_t ws_size,
                              hipStream_t stream) {
  const float* x     = (const float*)d_in[0];  // [B,S,D] fp32
  const float* freqs = (const float*)d_in[1];  // [S,HD] fp32
  const float* Wqkv  = (const float*)d_in[2];  // [3072,2048] fp32
  const float* Wo    = (const float*)d_in[3];  // [2048,2048] fp32
  float* out = (float*)d_out;                  // [B,S,D] fp32

  short* ws     = (short*)d_ws;
  short* xb     = ws;                                    // 4096*2048
  short* Wob    = ws;                                    // 2048*2048 (alias xb)
  short* Wqkvb  = ws + (size_t)4096 * 2048;              // 3072*2048
  short* xqkv   = Wqkvb + (size_t)QKV_ * 2048;           // 4096*3072
  short* attn   = xqkv;                                  // 4096*2048 (alias)
  short* Qr     = xqkv + (size_t)4096 * QKV_;
  short* Kr     = Qr + (size_t)B_ * NH_ * S_ * HD_;
  short* Vv     = Kr + (size_t)B_ * NKV_ * S_ * HD_;
  short* Vtg    = Vv + (size_t)B_ * NKV_ * S_ * HD_;
  // total ~41.9M shorts = 83.9 MB

  f32_to_bf16<<<(4096 * 2048 / 8) / 256, 256, 0, stream>>>(x, xb, 4096 * 2048 / 8);
  f32_to_bf16<<<(QKV_ * 2048 / 8) / 256, 256, 0, stream>>>(Wqkv, Wqkvb, QKV_ * 2048 / 8);
  gemm_nt_bf16<QKV_, 2048, false>
      <<<dim3(QKV_ / 128, 4096 / 128), 256, 0, stream>>>(xb, Wqkvb, xqkv);
  f32_to_bf16<<<(2048 * 2048 / 8) / 256, 256, 0, stream>>>(Wo, Wob, 2048 * 2048 / 8);
  rope_split<<<(B_ * S_ * QKV_ / 8) / 256, 256, 0, stream>>>(xqkv, freqs, Qr, Kr, Vv);
  transpose_v<<<dim3(S_ / 64, HD_ / 64, B_ * NKV_), 256, 0, stream>>>(Vv, Vtg);
  attn_causal<<<dim3(16, B_ * NH_), 256, 0, stream>>>(Qr, Kr, Vtg, attn);
  gemm_nt_bf16<2048, 2048, true>
      <<<dim3(2048 / 128, 4096 / 128), 256, 0, stream>>>(attn, Wob, out);
}

// Round 9
// 316.951 us; speedup vs baseline: 1.7058x; 1.0370x over previous
//
#include <hip/hip_runtime.h>
#include <hip/hip_bf16.h>
#include <cstdint>
#include <cstddef>

#define B_ 2
#define S_ 2048
#define NH_ 16
#define NKV_ 4
#define HD_ 128
#define QDIM_ 2048
#define KVDIM_ 512
#define QKV_ 3072

typedef __attribute__((ext_vector_type(8))) short short8;
typedef __attribute__((ext_vector_type(4))) short bhalf4;   // short4 collides with HIP
typedef __attribute__((ext_vector_type(4))) float float4v;

__device__ __forceinline__ float bf2f(short u) {
  union { unsigned int i; float f; } v;
  v.i = ((unsigned int)(unsigned short)u) << 16;
  return v.f;
}
__device__ __forceinline__ short f2bf(float f) {
  union { float f; unsigned int i; } v; v.f = f;
  unsigned int x = v.i;
  x += 0x7fffu + ((x >> 16) & 1u);   // RNE
  return (short)(x >> 16);
}

__device__ __forceinline__ void async_copy16(void* lds, const void* g) {
  __builtin_amdgcn_global_load_lds(
      (const __attribute__((address_space(1))) void*)g,
      (__attribute__((address_space(3))) void*)lds, 16, 0, 0);
}

// ---------------------------------------------------------------------------
// fp32 -> bf16 convert (HBM-bound). n8 = element count / 8.
// ---------------------------------------------------------------------------
__global__ void f32_to_bf16(const float* __restrict__ src, short* __restrict__ dst,
                            int n8) {
  int id = blockIdx.x * 256 + threadIdx.x;
  if (id >= n8) return;
  const float* f = src + (size_t)id * 8;
  float4v a = *(const float4v*)(f);
  float4v b = *(const float4v*)(f + 4);
  short8 r;
#pragma unroll
  for (int e = 0; e < 4; ++e) { r[e] = f2bf(a[e]); r[4 + e] = f2bf(b[e]); }
  *(short8*)(dst + (size_t)id * 8) = r;
}

// ---------------------------------------------------------------------------
// NT GEMM, pure bf16 operands (unchanged — shape plateau; attn first).
// ---------------------------------------------------------------------------
template <int N, int K, bool CF32>
__global__ __launch_bounds__(256)
void gemm_nt_bf16(const short* __restrict__ A, const short* __restrict__ Bm,
                  void* __restrict__ Cp) {
  __shared__ __align__(16) short sA[128 * 32];
  __shared__ __align__(16) short sB[128 * 32];
  const int tid = threadIdx.x;
  const int m0 = blockIdx.y * 128, n0 = blockIdx.x * 128;
  const int wave = tid >> 6, lane = tid & 63;
  const int wm = (wave & 1) << 6, wn = (wave >> 1) << 6;
  const int lm = lane & 15, kg = lane >> 4;

  float4v acc[4][4];
#pragma unroll
  for (int i = 0; i < 4; ++i)
#pragma unroll
    for (int j = 0; j < 4; ++j)
      acc[i][j] = (float4v){0.f, 0.f, 0.f, 0.f};

  const int r0 = tid >> 2, c0 = tid & 3;
  const short* gA0 = A + (size_t)(m0 + r0) * K + c0 * 8;
  const short* gA1 = gA0 + (size_t)64 * K;
  const short* gB0 = Bm + (size_t)(n0 + r0) * K + c0 * 8;
  const short* gB1 = gB0 + (size_t)64 * K;
  short* lA0 = sA + tid * 8;
  short* lA1 = sA + 2048 + tid * 8;
  short* lB0 = sB + tid * 8;
  short* lB1 = sB + 2048 + tid * 8;

  for (int k0 = 0; k0 < K; k0 += 32) {
    async_copy16(lA0, gA0 + k0);
    async_copy16(lA1, gA1 + k0);
    async_copy16(lB0, gB0 + k0);
    async_copy16(lB1, gB1 + k0);
    __syncthreads();

    short8 a[4], b[4];
#pragma unroll
    for (int i = 0; i < 4; ++i)
      a[i] = *(const short8*)(sA + (wm + i * 16 + lm) * 32 + kg * 8);
#pragma unroll
    for (int j = 0; j < 4; ++j)
      b[j] = *(const short8*)(sB + (wn + j * 16 + lm) * 32 + kg * 8);
#pragma unroll
    for (int i = 0; i < 4; ++i)
#pragma unroll
      for (int j = 0; j < 4; ++j)
        acc[i][j] = __builtin_amdgcn_mfma_f32_16x16x32_bf16(a[i], b[j], acc[i][j], 0, 0, 0);
    __syncthreads();
  }

#pragma unroll
  for (int i = 0; i < 4; ++i) {
    const int rb = m0 + wm + i * 16 + kg * 4;
#pragma unroll
    for (int j = 0; j < 4; ++j) {
      const int cc = n0 + wn + j * 16 + lm;
#pragma unroll
      for (int r = 0; r < 4; ++r) {
        if constexpr (CF32)
          ((float*)Cp)[(size_t)(rb + r) * N + cc] = acc[i][j][r];
        else
          ((short*)Cp)[(size_t)(rb + r) * N + cc] = f2bf(acc[i][j][r]);
      }
    }
  }
}

// ---------------------------------------------------------------------------
// RoPE + split/layout; Q pre-scaled by 1/sqrt(HD).
// ---------------------------------------------------------------------------
__global__ void rope_split(const short* __restrict__ xqkv, const float* __restrict__ freqs,
                           short* __restrict__ Qr, short* __restrict__ Kr,
                           short* __restrict__ Vv) {
  const int id = blockIdx.x * 256 + threadIdx.x;
  const int i = id / (QKV_ / 8);   // token 0..4095
  const int c8 = id % (QKV_ / 8);
  const int col = c8 * 8;
  const int b = i >> 11, s = i & (S_ - 1);
  short8 xv = *(const short8*)(xqkv + (size_t)i * QKV_ + col);
  if (col < QDIM_ + KVDIM_) {
    int d;
    short* dst;
    float sc;
    if (col < QDIM_) {
      int hh = col >> 7; d = col & 127;
      dst = Qr + ((size_t)(b * NH_ + hh) * S_ + s) * HD_ + d;
      sc = 0.08838834764831845f;   // 1/sqrt(128)
    } else {
      int cc = col - QDIM_;
      int hh = cc >> 7; d = cc & 127;
      dst = Kr + ((size_t)(b * NKV_ + hh) * S_ + s) * HD_ + d;
      sc = 1.0f;
    }
    const float* fp = freqs + (size_t)s * HD_ + d;
    float4v fa = *(const float4v*)(fp);
    float4v fb = *(const float4v*)(fp + 4);
    float ff[8] = {fa[0], fa[1], fa[2], fa[3], fb[0], fb[1], fb[2], fb[3]};
    short8 ov;
#pragma unroll
    for (int pp = 0; pp < 4; ++pp) {
      float t0 = bf2f(xv[2 * pp]), t1 = bf2f(xv[2 * pp + 1]);
      float f0 = ff[2 * pp], f1 = ff[2 * pp + 1];
      ov[2 * pp]     = f2bf((t0 * f1 - t1 * f0) * sc);
      ov[2 * pp + 1] = f2bf((t0 * f0 + t1 * f1) * sc);
    }
    *(short8*)dst = ov;
  } else {
    int cc = col - QDIM_ - KVDIM_;
    int hh = cc >> 7, d = cc & 127;
    *(short8*)(Vv + ((size_t)(b * NKV_ + hh) * S_ + s) * HD_ + d) = xv;
  }
}

// ---------------------------------------------------------------------------
// V transpose: Vv [b][kvh][s][d] -> Vt [b][kvh][d][s]. LDS-tiled 64x64.
// ---------------------------------------------------------------------------
__global__ void transpose_v(const short* __restrict__ Vv, short* __restrict__ Vt) {
  __shared__ short t[64][72];
  const int s0 = blockIdx.x * 64, d0 = blockIdx.y * 64;
  const short* src = Vv + (size_t)blockIdx.z * S_ * HD_;
  short* dst = Vt + (size_t)blockIdx.z * S_ * HD_;
  const int tid = threadIdx.x;
#pragma unroll
  for (int c = 0; c < 2; ++c) {
    int ch = tid + 256 * c;
    int row = ch >> 3, kc = ch & 7;
    *(short8*)(&t[row][kc * 8]) =
        *(const short8*)(src + (size_t)(s0 + row) * HD_ + d0 + kc * 8);
  }
  __syncthreads();
#pragma unroll
  for (int c = 0; c < 2; ++c) {
    int ch = tid + 256 * c;
    int drow = ch >> 3, sc = ch & 7;
    short8 w;
#pragma unroll
    for (int j = 0; j < 8; ++j) w[j] = t[sc * 8 + j][drow];
    *(short8*)(dst + (size_t)(d0 + drow) * S_ + s0 + sc * 8) = w;
  }
}

// ---------------------------------------------------------------------------
// Flash attention v5: S^T formulation + software-pipelined K-loop.
// Both halves (q-tiles pair, 31-pair) share the SAME K/V stream -> unified
// 33-step loop; double-buffered sK/sVt; prefetch step s+1 issued right after
// the barrier, so the vmcnt(0) drain at the next barrier finds loads already
// landed (one full tile of compute in between). One barrier per tile.
// ---------------------------------------------------------------------------
#define TK 64

__global__ __launch_bounds__(256)
void attn_causal(const short* __restrict__ Q, const short* __restrict__ K,
                 const short* __restrict__ Vt, short* __restrict__ O) {
  const int pair = blockIdx.x;   // 0..15
  const int bh = blockIdx.y;     // 0..31
  const int b = bh >> 4, h = bh & 15;
  const int kvh = h >> 2;
  const int tid = threadIdx.x, wave = tid >> 6, lane = tid & 63;
  const int lm = lane & 15, kg = lane >> 4;

  __shared__ __align__(16) short sK[2][TK * HD_];    // 2 x 16KB, swizzled
  __shared__ __align__(16) short sVt[2][HD_ * TK];   // 2 x 16KB, swizzled
  __shared__ __align__(16) short sO[4 * 16 * 128];   // per-wave O^T scratch

  const short* Qb = Q + (size_t)(b * NH_ + h) * S_ * HD_;
  const short* Kb = K + (size_t)(b * NKV_ + kvh) * S_ * HD_;
  const short* Vtb = Vt + (size_t)(b * NKV_ + kvh) * S_ * HD_;

  const int qt0 = pair, qt1 = 31 - pair;
  const int n0 = qt0 + 1;          // steps in half 0; total steps = 33

  // ---- stage tile (k0) into buffer bf ----
  auto stage = [&](int k0, int bf) {
#pragma unroll
    for (int c = 0; c < 4; ++c) {
      int ch = tid + 256 * c;
      int row = ch >> 4, kc = ch & 15;
      async_copy16(sK[bf] + ch * 8,
                   Kb + (size_t)(k0 + row) * HD_ + (kc ^ (row & 7)) * 8);
    }
#pragma unroll
    for (int c = 0; c < 4; ++c) {
      int ch = tid + 256 * c;
      int row = ch >> 3, kc = ch & 7;
      async_copy16(sVt[bf] + ch * 8,
                   Vtb + (size_t)row * S_ + k0 + (kc ^ (row & 7)) * 8);
    }
  };

  // ---- per-half state ----
  int qglob = qt0 * 64 + wave * 16 + lm;
  short8 qf[4];
#pragma unroll
  for (int kk = 0; kk < 4; ++kk)
    qf[kk] = *(const short8*)(Qb + (size_t)qglob * HD_ + kk * 32 + kg * 8);
  float mcur = -1e9f, lcur = 0.f;
  float4v o[8];
#pragma unroll
  for (int df = 0; df < 8; ++df) o[df] = (float4v){0.f, 0.f, 0.f, 0.f};

  auto epilogue = [&](int q0w) {
    float inv = 1.f / lcur;
    short* myO = sO + wave * 2048;   // [16 q][128 d]
#pragma unroll
    for (int df = 0; df < 8; ++df) {
      unsigned int p0 = (unsigned short)f2bf(o[df][0] * inv) |
                        ((unsigned int)(unsigned short)f2bf(o[df][1] * inv) << 16);
      unsigned int p1 = (unsigned short)f2bf(o[df][2] * inv) |
                        ((unsigned int)(unsigned short)f2bf(o[df][3] * inv) << 16);
      int base = lm * 128 + df * 16 + kg * 4;
      *(unsigned int*)(myO + base) = p0;
      *(unsigned int*)(myO + base + 2) = p1;
    }
    int q = lane >> 2, dp = (lane & 3) * 32;   // wave-private scratch
    const size_t rowoff = (size_t)(b * S_ + q0w + q) * QDIM_ + h * HD_ + dp;
#pragma unroll
    for (int e = 0; e < 4; ++e) {
      short8 w = *(const short8*)(myO + q * 128 + dp + e * 8);
      *(short8*)(O + rowoff + e * 8) = w;
    }
  };

  stage(0, 0);   // preload step 0 (half 0, k0=0)

  for (int s = 0; s < 33; ++s) {
    const int bf = s & 1;
    const bool h1 = (s >= n0);
    const int k0 = (h1 ? (s - n0) : s) * TK;
    const bool diag = h1 ? (s == 32) : (s == qt0);

    __syncthreads();   // drains loads for step s; prior buf reads all done
    if (s + 1 < 33) {
      int sn = s + 1;
      int k0n = ((sn >= n0) ? (sn - n0) : sn) * TK;
      stage(k0n, sn & 1);
    }

    // S^T = K * Q^T
    float4v sfT[4];
#pragma unroll
    for (int mj = 0; mj < 4; ++mj) sfT[mj] = (float4v){0.f, 0.f, 0.f, 0.f};
#pragma unroll
    for (int kk = 0; kk < 4; ++kk) {
      int kd = kk * 4 + kg;
#pragma unroll
      for (int mj = 0; mj < 4; ++mj) {
        int row = mj * 16 + lm;
        short8 af = *(const short8*)(sK[bf] + row * HD_ + (kd ^ (row & 7)) * 8);
        sfT[mj] = __builtin_amdgcn_mfma_f32_16x16x32_bf16(af, qf[kk], sfT[mj], 0, 0, 0);
      }
    }

    if (diag) {
#pragma unroll
      for (int mj = 0; mj < 4; ++mj)
#pragma unroll
        for (int r = 0; r < 4; ++r) {
          int kcol = k0 + mj * 16 + kg * 4 + r;
          sfT[mj][r] = (kcol <= qglob) ? sfT[mj][r] : -3e38f;
        }
    }

    // online softmax for this lane's q column
    float mx = -3e38f;
#pragma unroll
    for (int mj = 0; mj < 4; ++mj)
#pragma unroll
      for (int r = 0; r < 4; ++r) mx = fmaxf(mx, sfT[mj][r]);
    mx = fmaxf(mx, __shfl_xor(mx, 16, 64));
    mx = fmaxf(mx, __shfl_xor(mx, 32, 64));
    float mnew = fmaxf(mcur, mx);
    float alpha = __expf(mcur - mnew);
    float rs = 0.f;
    bhalf4 pb[4];   // P^T B-frags for x16 MFMA: B[n=q][k=t*16+kg*4+j]
#pragma unroll
    for (int t = 0; t < 4; ++t)
#pragma unroll
      for (int r = 0; r < 4; ++r) {
        float e = __expf(sfT[t][r] - mnew);
        rs += e;
        pb[t][r] = f2bf(e);
      }
    rs += __shfl_xor(rs, 16, 64);
    rs += __shfl_xor(rs, 32, 64);
    mcur = mnew;
    lcur = lcur * alpha + rs;
#pragma unroll
    for (int df = 0; df < 8; ++df)
#pragma unroll
      for (int r = 0; r < 4; ++r) o[df][r] *= alpha;

    // O^T += V^T * P^T  (x16 MFMA, 4 k-chunks of 16)
#pragma unroll
    for (int t = 0; t < 4; ++t) {
      int kc = t * 2 + (kg >> 1);
#pragma unroll
      for (int df = 0; df < 8; ++df) {
        int row = df * 16 + lm;
        bhalf4 va = *(const bhalf4*)(sVt[bf] + row * TK + (kc ^ (row & 7)) * 8 +
                                     (kg & 1) * 4);
        o[df] = __builtin_amdgcn_mfma_f32_16x16x16bf16_1k(va, pb[t], o[df], 0, 0, 0);
      }
    }

    if (s == n0 - 1) {
      // finish half 0, switch to half 1 (prefetch for its tile 0 in flight)
      epilogue(qt0 * 64 + wave * 16);
      qglob = qt1 * 64 + wave * 16 + lm;
#pragma unroll
      for (int kk = 0; kk < 4; ++kk)
        qf[kk] = *(const short8*)(Qb + (size_t)qglob * HD_ + kk * 32 + kg * 8);
      mcur = -1e9f; lcur = 0.f;
#pragma unroll
      for (int df = 0; df < 8; ++df) o[df] = (float4v){0.f, 0.f, 0.f, 0.f};
    }
  }

  epilogue(qt1 * 64 + wave * 16);
}

// ---------------------------------------------------------------------------
extern "C" void kernel_launch(void* const* d_in, const int* in_sizes, int n_in,
                              void* d_out, int out_size, void* d_ws, size_t ws_size,
                              hipStream_t stream) {
  const float* x     = (const float*)d_in[0];  // [B,S,D] fp32
  const float* freqs = (const float*)d_in[1];  // [S,HD] fp32
  const float* Wqkv  = (const float*)d_in[2];  // [3072,2048] fp32
  const float* Wo    = (const float*)d_in[3];  // [2048,2048] fp32
  float* out = (float*)d_out;                  // [B,S,D] fp32

  short* ws     = (short*)d_ws;
  short* xb     = ws;                                    // 4096*2048
  short* Wob    = ws;                                    // 2048*2048 (alias xb)
  short* Wqkvb  = ws + (size_t)4096 * 2048;              // 3072*2048
  short* xqkv   = Wqkvb + (size_t)QKV_ * 2048;           // 4096*3072
  short* attn   = xqkv;                                  // 4096*2048 (alias)
  short* Qr     = xqkv + (size_t)4096 * QKV_;
  short* Kr     = Qr + (size_t)B_ * NH_ * S_ * HD_;
  short* Vv     = Kr + (size_t)B_ * NKV_ * S_ * HD_;
  short* Vtg    = Vv + (size_t)B_ * NKV_ * S_ * HD_;
  // total ~41.9M shorts = 83.9 MB

  f32_to_bf16<<<(4096 * 2048 / 8) / 256, 256, 0, stream>>>(x, xb, 4096 * 2048 / 8);
  f32_to_bf16<<<(QKV_ * 2048 / 8) / 256, 256, 0, stream>>>(Wqkv, Wqkvb, QKV_ * 2048 / 8);
  gemm_nt_bf16<QKV_, 2048, false>
      <<<dim3(QKV_ / 128, 4096 / 128), 256, 0, stream>>>(xb, Wqkvb, xqkv);
  f32_to_bf16<<<(2048 * 2048 / 8) / 256, 256, 0, stream>>>(Wo, Wob, 2048 * 2048 / 8);
  rope_split<<<(B_ * S_ * QKV_ / 8) / 256, 256, 0, stream>>>(xqkv, freqs, Qr, Kr, Vv);
  transpose_v<<<dim3(S_ / 64, HD_ / 64, B_ * NKV_), 256, 0, stream>>>(Vv, Vtg);
  attn_causal<<<dim3(16, B_ * NH_), 256, 0, stream>>>(Qr, Kr, Vtg, attn);
  gemm_nt_bf16<2048, 2048, true>
      <<<dim3(2048 / 128, 4096 / 128), 256, 0, stream>>>(attn, Wob, out);
}